// Round 7
// baseline (505.919 us; speedup 1.0000x reference)
//
#include <hip/hip_runtime.h>
#include <hip/hip_bf16.h>

#define CEPS 1e-8f

typedef __attribute__((ext_vector_type(8))) __bf16 bf16x8;
typedef __attribute__((ext_vector_type(4))) float f32x4;

__device__ __forceinline__ void gload_lds16(const void* g, void* l) {
  __builtin_amdgcn_global_load_lds((const __attribute__((address_space(1))) unsigned int*)g,
                                   (__attribute__((address_space(3))) unsigned int*)l, 16, 0, 0);
}

__device__ __forceinline__ float gelu_f(float v) {
  return 0.5f * v * (1.0f + erff(v * 0.70710678118654752f));
}

// ---------- magnitude + concat(bf16) + row norm ----------
__global__ __launch_bounds__(256) void k_mag(const float* __restrict__ re, const float* __restrict__ im,
                                             float* __restrict__ mag, __hip_bfloat16* __restrict__ xcat,
                                             float* __restrict__ xn) {
  int row = blockIdx.x;  // 0..2047
  const float* r = re + (size_t)row * 512;
  const float* q = im + (size_t)row * 512;
  double ss = 0.0;
  for (int d = threadIdx.x; d < 512; d += 256) {
    float a = r[d], b = q[d];
    float s = __fadd_rn(__fmul_rn(a, a), __fmul_rn(b, b));  // match np rounding
    float m = __fsqrt_rn(s);
    mag[(size_t)row * 512 + d] = m;
    xcat[(size_t)row * 1024 + d] = __float2bfloat16(a);
    xcat[(size_t)row * 1024 + 512 + d] = __float2bfloat16(b);
    ss += (double)m * (double)m;
  }
  for (int off = 32; off; off >>= 1) ss += __shfl_xor(ss, off);
  __shared__ double red[4];
  int lane = threadIdx.x & 63, wave = threadIdx.x >> 6;
  if (lane == 0) red[wave] = ss;
  __syncthreads();
  if (threadIdx.x == 0) {
    double tot = red[0] + red[1] + red[2] + red[3];
    float n = (float)sqrt(tot);
    xn[row] = fmaxf(n, CEPS);
  }
}

// ---------- concept magnitude (transposed) + norms ----------
__global__ __launch_bounds__(256) void k_cmag(const float* __restrict__ cre, const float* __restrict__ cim,
                                              float* __restrict__ cmagT, float* __restrict__ yn) {
  int c = blockIdx.x;  // 0..999
  const float* r = cre + (size_t)c * 512;
  const float* q = cim + (size_t)c * 512;
  double ss = 0.0;
  for (int d = threadIdx.x; d < 512; d += 256) {
    float a = r[d], b = q[d];
    float s = __fadd_rn(__fmul_rn(a, a), __fmul_rn(b, b));
    float m = __fsqrt_rn(s);
    cmagT[(size_t)d * 1000 + c] = m;
    ss += (double)m * (double)m;
  }
  for (int off = 32; off; off >>= 1) ss += __shfl_xor(ss, off);
  __shared__ double red[4];
  int lane = threadIdx.x & 63, wave = threadIdx.x >> 6;
  if (lane == 0) red[wave] = ss;
  __syncthreads();
  if (threadIdx.x == 0) {
    double tot = red[0] + red[1] + red[2] + red[3];
    float n = (float)sqrt(tot);
    yn[c] = fmaxf(n, CEPS);
  }
}

// ---------- dots GEMM, f64 accumulation; inputs converted to f64 ONCE in LDS (exact) ----------
// Inner loop is pure v_fma_f64 (was cvt+cvt+fma per MAC). Accumulation class unchanged (f64).
__global__ __launch_bounds__(256) void k_dots(const float* __restrict__ A, const float* __restrict__ Bm,
                                              float* __restrict__ Cm, int M, int N, int K, int ldc,
                                              const float* __restrict__ xn, const float* __restrict__ yn) {
  __shared__ double As[16][64];
  __shared__ double Bs[16][64];
  const int tid = threadIdx.x;
  const int m0 = blockIdx.y * 64, n0 = blockIdx.x * 64;
  const int tx = tid & 15, ty = tid >> 4;
  const int ar = tid >> 2, ak = (tid & 3) << 2;
  const int bk = tid >> 4, bn = (tid & 15) << 2;
  double acc[4][4] = {};
  for (int k0 = 0; k0 < K; k0 += 16) {
    float4 a4 = *(const float4*)(A + (size_t)(m0 + ar) * K + k0 + ak);
    As[ak + 0][ar] = (double)a4.x; As[ak + 1][ar] = (double)a4.y;
    As[ak + 2][ar] = (double)a4.z; As[ak + 3][ar] = (double)a4.w;
    float4 b4 = make_float4(0.f, 0.f, 0.f, 0.f);
    if (n0 + bn < N) b4 = *(const float4*)(Bm + (size_t)(k0 + bk) * N + n0 + bn);
    Bs[bk][bn + 0] = (double)b4.x; Bs[bk][bn + 1] = (double)b4.y;
    Bs[bk][bn + 2] = (double)b4.z; Bs[bk][bn + 3] = (double)b4.w;
    __syncthreads();
#pragma unroll
    for (int kk = 0; kk < 16; ++kk) {
      double av[4], bv[4];
#pragma unroll
      for (int i = 0; i < 4; ++i) av[i] = As[kk][ty * 4 + i];
#pragma unroll
      for (int j = 0; j < 4; ++j) bv[j] = Bs[kk][tx * 4 + j];
#pragma unroll
      for (int i = 0; i < 4; ++i)
#pragma unroll
        for (int j = 0; j < 4; ++j)
          acc[i][j] = fma(av[i], bv[j], acc[i][j]);
    }
    __syncthreads();
  }
#pragma unroll
  for (int i = 0; i < 4; ++i) {
    int row = m0 + ty * 4 + i;
#pragma unroll
    for (int j = 0; j < 4; ++j) {
      int col = n0 + tx * 4 + j;
      if (col >= N) continue;
      double d = acc[i][j] / ((double)xn[row] * (double)yn[col]);
      Cm[(size_t)row * ldc + col] = (float)d;
    }
  }
}

// ---------- top-5 per row (one wave per row) ----------
__global__ __launch_bounds__(256) void k_topk(const float* __restrict__ sims,
                                              float* __restrict__ top_sims, float* __restrict__ top_idx) {
  int lane = threadIdx.x & 63, wave = threadIdx.x >> 6;
  int row = blockIdx.x * 4 + wave;
  const float* s = sims + (size_t)row * 1000;
  float v[16];
  int idx[16];
#pragma unroll
  for (int t = 0; t < 16; ++t) {
    int c = lane + t * 64;
    if (c < 1000) { v[t] = s[c]; idx[t] = c; }
    else { v[t] = -1e30f; idx[t] = 1 << 20; }
  }
  for (int j = 0; j < 5; ++j) {
    float bv = -1e30f; int bi = 1 << 20;
#pragma unroll
    for (int t = 0; t < 16; ++t) {
      if (v[t] > bv || (v[t] == bv && idx[t] < bi)) { bv = v[t]; bi = idx[t]; }
    }
    float rv = bv; int ri = bi;
#pragma unroll
    for (int off = 32; off; off >>= 1) {
      float ov = __shfl_xor(rv, off);
      int oi = __shfl_xor(ri, off);
      if (ov > rv || (ov == rv && oi < ri)) { rv = ov; ri = oi; }
    }
    if (lane == 0) {
      top_sims[(size_t)row * 5 + j] = rv;
      top_idx[(size_t)row * 5 + j] = (float)ri;
    }
#pragma unroll
    for (int t = 0; t < 16; ++t)
      if (idx[t] == ri) v[t] = -1e30f;
  }
}

// ---------- generic transpose + bf16 convert: W[K,N] f32 -> Wt[Nout rows][K] bf16 (zero-pad n>=N) ----------
__global__ __launch_bounds__(256) void k_tr(const float* __restrict__ W, __hip_bfloat16* __restrict__ Wt,
                                            int K, int N) {
  __shared__ float t32[64][65];
  int n0 = blockIdx.x * 64, k0 = blockIdx.y * 64;
  int tid = threadIdx.x;
  {
    int nc = tid & 15, kr4 = tid >> 4;
#pragma unroll
    for (int p = 0; p < 4; ++p) {
      int kr = p * 16 + kr4;
      int n = n0 + nc * 4;
      float4 v = make_float4(0.f, 0.f, 0.f, 0.f);
      if (n < N) v = *(const float4*)(W + (size_t)(k0 + kr) * N + n);
      t32[kr][nc * 4 + 0] = v.x; t32[kr][nc * 4 + 1] = v.y;
      t32[kr][nc * 4 + 2] = v.z; t32[kr][nc * 4 + 3] = v.w;
    }
  }
  __syncthreads();
  {
    int kc = tid & 15, nr4 = tid >> 4;
#pragma unroll
    for (int p = 0; p < 4; ++p) {
      int nr = p * 16 + nr4;
      ushort4 o;
      {
        __hip_bfloat16 h0 = __float2bfloat16(t32[kc * 4 + 0][nr]);
        __hip_bfloat16 h1 = __float2bfloat16(t32[kc * 4 + 1][nr]);
        __hip_bfloat16 h2 = __float2bfloat16(t32[kc * 4 + 2][nr]);
        __hip_bfloat16 h3 = __float2bfloat16(t32[kc * 4 + 3][nr]);
        o.x = *(unsigned short*)&h0; o.y = *(unsigned short*)&h1;
        o.z = *(unsigned short*)&h2; o.w = *(unsigned short*)&h3;
      }
      *(ushort4*)((unsigned short*)Wt + (size_t)(n0 + nr) * K + k0 + kc * 4) = o;
    }
  }
}

// ---------- 128x128 bf16 MFMA GEMM with gelu+bf16 epilogue (MLP layers) ----------
__global__ __launch_bounds__(256) void gemm_mfma_bt(const __hip_bfloat16* __restrict__ A,
                                                    const __hip_bfloat16* __restrict__ Bt,
                                                    __hip_bfloat16* __restrict__ C, int M, int N, int K,
                                                    int ldc, const float* __restrict__ bias) {
  __shared__ short Al[128 * 32];
  __shared__ short Bl[128 * 32];
  const int tid = threadIdx.x, lane = tid & 63, wave = tid >> 6;
  const int m0 = blockIdx.y * 128, n0 = blockIdx.x * 128;
  const int wr = wave >> 1, wc = wave & 1;
  f32x4 acc[4][4];
  f32x4 zero4 = {0.f, 0.f, 0.f, 0.f};
#pragma unroll
  for (int i = 0; i < 4; ++i)
#pragma unroll
    for (int j = 0; j < 4; ++j) acc[i][j] = zero4;

  const short* Ag = (const short*)A;
  const short* Bg = (const short*)Bt;
  for (int k0 = 0; k0 < K; k0 += 32) {
#pragma unroll
    for (int s = 0; s < 2; ++s) {
      int seg = wave + s * 4;
      int elem = seg * 512 + lane * 8;
      int row = elem >> 5, kk = elem & 31;
      gload_lds16(Ag + (size_t)(m0 + row) * K + k0 + kk, Al + elem);
      gload_lds16(Bg + (size_t)(n0 + row) * K + k0 + kk, Bl + elem);
    }
    __syncthreads();
    bf16x8 af[4], bfr[4];
    const int fr = lane & 15, fk = (lane >> 4) << 3;
#pragma unroll
    for (int i = 0; i < 4; ++i)
      af[i] = *(const bf16x8*)(Al + (wr * 64 + i * 16 + fr) * 32 + fk);
#pragma unroll
    for (int j = 0; j < 4; ++j)
      bfr[j] = *(const bf16x8*)(Bl + (wc * 64 + j * 16 + fr) * 32 + fk);
#pragma unroll
    for (int i = 0; i < 4; ++i)
#pragma unroll
      for (int j = 0; j < 4; ++j)
        acc[i][j] = __builtin_amdgcn_mfma_f32_16x16x32_bf16(af[i], bfr[j], acc[i][j], 0, 0, 0);
    __syncthreads();
  }
  const int fr = lane & 15, fq = lane >> 4;
#pragma unroll
  for (int j = 0; j < 4; ++j) {
    int col = n0 + wc * 64 + j * 16 + fr;
    if (col >= N) continue;
    float bv = bias[col];
#pragma unroll
    for (int i = 0; i < 4; ++i) {
      int rbase = m0 + wr * 64 + i * 16 + fq * 4;
#pragma unroll
      for (int r = 0; r < 4; ++r)
        C[(size_t)(rbase + r) * ldc + col] = __float2bfloat16(gelu_f(acc[i][j][r] + bv));
    }
  }
}

// ---------- persistent 256x256 8-phase bf16 MFMA GEMM (final layer) ----------
// Swapped-operand MFMA: mfma(bfr, af) -> lane holds row=(lane&15), cols=(lane>>4)*4+r
// (4 consecutive C columns) => dump is 32 dwordx4 stores + 4 float4 bias loads.
// Dump discipline: vmcnt(0) pre-dump (drains only last A/B loads), skip ph4 vmcnt on dump
// iterations => dump stores never force-drained before ph8 (~6 phases slack). Robust to codegen.
// Minimal sched_barrier: only rule-#18 fence after lgkmcnt(0).
__global__ __launch_bounds__(512, 2) void gemm_mfma8(const __hip_bfloat16* __restrict__ A,
                                                     const __hip_bfloat16* __restrict__ Bt,
                                                     float* __restrict__ C,
                                                     const float* __restrict__ bias) {
  const int KNT = 12;  // K/64
  const int Kd = 768, Nd = 50000, ldc = 50000;
  __shared__ short As[2][16384];
  __shared__ short Bs[2][16384];
  const int tid = threadIdx.x, lane = tid & 63, wave = tid >> 6;
  const int wm = wave >> 2, wn = wave & 3;

  const int xcd = blockIdx.x & 7, jb = blockIdx.x >> 3;
  const int tbase = xcd * 196 + jb;          // tile t: tbase + 32*t  (32 blocks/XCD share 4 B panels)
  const int T = 6 + (jb < 4 ? 1 : 0);
  const int G = T * KNT;                     // even

  const short* Ag = (const short*)A;
  const short* Bg = (const short*)Bt;

  f32x4 acc[8][4];
  f32x4 z4 = {0.f, 0.f, 0.f, 0.f};
#pragma unroll
  for (int i = 0; i < 8; ++i)
#pragma unroll
    for (int j = 0; j < 4; ++j) acc[i][j] = z4;

  auto stageA2 = [&](int g) {
    if (g >= G) return;
    const int tile = tbase + (g / KNT) * 32;
    const int k0 = (g % KNT) * 64;
    const int m0g = (tile & 7) << 8;
    const int buf = g & 1;
#pragma unroll
    for (int r = 0; r < 4; ++r) {
      int idx = r * 512 + tid;
      int row = idx >> 3;
      int ch = (idx & 7) ^ (row & 7);
      gload_lds16(Ag + (size_t)(m0g + row) * Kd + k0 + ch * 8, &As[buf][row * 64 + (idx & 7) * 8]);
    }
  };
  auto stageB2 = [&](int g) {
    if (g >= G) return;
    const int tile = tbase + (g / KNT) * 32;
    const int k0 = (g % KNT) * 64;
    const int n0g = (tile >> 3) << 8;
    const int buf = g & 1;
#pragma unroll
    for (int r = 0; r < 4; ++r) {
      int idx = r * 512 + tid;
      int row = idx >> 3;
      int ch = (idx & 7) ^ (row & 7);
      gload_lds16(Bg + (size_t)(n0g + row) * Kd + k0 + ch * 8, &Bs[buf][row * 64 + (idx & 7) * 8]);
    }
  };

  bf16x8 af[4][2], bf0[2][2], bf1[2][2];
  auto readA = [&](int buf, int mh) {
#pragma unroll
    for (int q = 0; q < 4; ++q) {
      int row = wm * 128 + (mh * 4 + q) * 16 + (lane & 15);
#pragma unroll
      for (int ks = 0; ks < 2; ++ks) {
        int ch = (ks * 4 + (lane >> 4)) ^ (row & 7);
        af[q][ks] = *(const bf16x8*)(&As[buf][row * 64 + ch * 8]);
      }
    }
  };
  auto readB = [&](int buf, int nh, bf16x8 bfr[2][2]) {
#pragma unroll
    for (int p = 0; p < 2; ++p) {
      int row = wn * 64 + (nh * 2 + p) * 16 + (lane & 15);
#pragma unroll
      for (int ks = 0; ks < 2; ++ks) {
        int ch = (ks * 4 + (lane >> 4)) ^ (row & 7);
        bfr[p][ks] = *(const bf16x8*)(&Bs[buf][row * 64 + ch * 8]);
      }
    }
  };
  // swapped operands: D row-side = bfr (C cols per-reg), col-side = af (C row = lane&15)
  auto domfma = [&](int mh, int p0, bf16x8 bfr[2][2]) {
    __builtin_amdgcn_s_setprio(1);
#pragma unroll
    for (int ks = 0; ks < 2; ++ks)
#pragma unroll
      for (int q = 0; q < 4; ++q)
#pragma unroll
        for (int p = 0; p < 2; ++p)
          acc[mh * 4 + q][p0 + p] =
              __builtin_amdgcn_mfma_f32_16x16x32_bf16(bfr[p][ks], af[q][ks], acc[mh * 4 + q][p0 + p], 0, 0, 0);
    __builtin_amdgcn_s_setprio(0);
  };
  auto dump = [&](int tile) {
    const int m0g = (tile & 7) << 8;
    const int n0g = (tile >> 3) << 8;
    const int colq = (lane >> 4) * 4;
    float4 bias4[4];
#pragma unroll
    for (int nj = 0; nj < 4; ++nj) {
      int colbase = n0g + wn * 64 + nj * 16 + colq;
      bias4[nj] = (colbase < Nd) ? *(const float4*)(bias + colbase) : make_float4(0.f, 0.f, 0.f, 0.f);
    }
#pragma unroll
    for (int mi = 0; mi < 8; ++mi) {
      int row = m0g + wm * 128 + mi * 16 + (lane & 15);
#pragma unroll
      for (int nj = 0; nj < 4; ++nj) {
        int colbase = n0g + wn * 64 + nj * 16 + colq;
        if (colbase < Nd) {
          f32x4 v = acc[mi][nj];
          float4 o = make_float4(v[0] + bias4[nj].x, v[1] + bias4[nj].y,
                                 v[2] + bias4[nj].z, v[3] + bias4[nj].w);
          *(float4*)(&C[(size_t)row * ldc + colbase]) = o;
        }
        acc[mi][nj] = z4;
      }
    }
  };

// phase: [reads/stage free region] -> s_barrier -> lgkmcnt(0) -> fence(rule#18) -> MFMA -> s_barrier
#define DO_PHASE(MH, P0, BFR)                                   \
  do {                                                          \
    __builtin_amdgcn_s_barrier();                               \
    asm volatile("s_waitcnt lgkmcnt(0)" ::: "memory");          \
    __builtin_amdgcn_sched_barrier(0);                          \
    domfma(MH, P0, BFR);                                        \
    __builtin_amdgcn_s_barrier();                               \
  } while (0)

  // ---- prologue: A0,B0,A1 staged; A0/B0 must land (A1 may fly) ----
  stageA2(0); stageB2(0); stageA2(1);
  asm volatile("s_waitcnt vmcnt(4)" ::: "memory");
  __builtin_amdgcn_s_barrier();

  const int iters = G / 2;
  for (int gi = 0; gi < iters; ++gi) {
    const int g1 = 2 * gi + 1, g2 = 2 * gi + 2, g3 = 2 * gi + 3;
    // pre-phase: stage B(g1) -> buf1 (B-region free since prev ph6)
    stageB2(g1);
    const bool dumpIter = (gi > 0) && ((2 * gi) % KNT) == 0;
    if (dumpIter) {
      // drain A(g1) [prev ph8] + B(g1) [just issued] so ph4 needs no wait over the stores
      asm volatile("s_waitcnt vmcnt(0)" ::: "memory");
      dump(tbase + ((2 * gi) / KNT - 1) * 32);
    }
    // ph1: Q(m0,n0) buf0 | reads A-mh0 + B-nh0
    readA(0, 0);
    readB(0, 0, bf0);
    DO_PHASE(0, 0, bf0);
    // ph2: Q(m0,n1) | reads B-nh1
    readB(0, 1, bf1);
    DO_PHASE(0, 2, bf1);
    // ph3: Q(m1,n1) | reads A-mh1
    readA(0, 1);
    DO_PHASE(1, 2, bf1);
    // ph4: Q(m1,n0) | stage A(g2); vmcnt(4) unless dump iter (A/B(g1) pre-drained)
    stageA2(g2);
    if (!dumpIter) asm volatile("s_waitcnt vmcnt(4)" ::: "memory");
    DO_PHASE(1, 0, bf0);
    // ph5: Q(m0,n0) buf1 | reads A-mh0 + B-nh0 | stage B(g2)
    readA(1, 0);
    readB(1, 0, bf0);
    stageB2(g2);
    DO_PHASE(0, 0, bf0);
    // ph6: Q(m0,n1) | reads B-nh1
    readB(1, 1, bf1);
    DO_PHASE(0, 2, bf1);
    // ph7: Q(m1,n1) | reads A-mh1
    readA(1, 1);
    DO_PHASE(1, 2, bf1);
    // ph8: Q(m1,n0) | stage A(g3); vmcnt(4) protects A/B(g2) for next ph1
    stageA2(g3);
    asm volatile("s_waitcnt vmcnt(4)" ::: "memory");
    DO_PHASE(1, 0, bf0);
  }
  dump(tbase + (T - 1) * 32);
#undef DO_PHASE
}

extern "C" void kernel_launch(void* const* d_in, const int* in_sizes, int n_in,
                              void* d_out, int out_size, void* d_ws, size_t ws_size,
                              hipStream_t stream) {
  const float* sre = (const float*)d_in[0];
  const float* simg = (const float*)d_in[1];
  const float* cre = (const float*)d_in[2];
  const float* cim = (const float*)d_in[3];
  const float* W1 = (const float*)d_in[4];
  const float* b1 = (const float*)d_in[5];
  const float* W2 = (const float*)d_in[6];
  const float* b2 = (const float*)d_in[7];
  const float* W3 = (const float*)d_in[8];
  const float* b3 = (const float*)d_in[9];
  const float* W4 = (const float*)d_in[10];
  const float* b4 = (const float*)d_in[11];

  const int M = 2048, D = 512, Cc = 1000, V = 50000, K1 = 1024, H3 = 768;
  const int Npad2 = 196 * 256;  // 50176

  char* ws = (char*)d_ws;
  size_t off = 0;
  auto alloc = [&](size_t bytes) {
    char* p = ws + off;
    off = (off + bytes + 255) & ~(size_t)255;
    return p;
  };
  __hip_bfloat16* xcatb = (__hip_bfloat16*)alloc((size_t)M * K1 * 2);
  float* mag = (float*)alloc((size_t)M * D * 4);
  float* cmagT = (float*)alloc((size_t)D * Cc * 4);
  float* xn = (float*)alloc((size_t)M * 4);
  float* yn = (float*)alloc((size_t)Cc * 4);
  float* simsb = (float*)alloc((size_t)M * Cc * 4);
  __hip_bfloat16* h1b = (__hip_bfloat16*)alloc((size_t)M * 512 * 2);
  __hip_bfloat16* h2b = (__hip_bfloat16*)alloc((size_t)M * 512 * 2);
  __hip_bfloat16* h3b = (__hip_bfloat16*)alloc((size_t)M * H3 * 2);
  __hip_bfloat16* w1t = (__hip_bfloat16*)alloc((size_t)512 * K1 * 2);
  __hip_bfloat16* w2t = (__hip_bfloat16*)alloc((size_t)512 * 512 * 2);
  __hip_bfloat16* w3t = (__hip_bfloat16*)alloc((size_t)H3 * 512 * 2);
  __hip_bfloat16* w4t = (__hip_bfloat16*)alloc((size_t)Npad2 * H3 * 2);

  float* top_sims = (float*)d_out;
  float* top_idx = (float*)d_out + (size_t)M * 5;
  float* logits = (float*)d_out + (size_t)M * 5 * 2;

  k_tr<<<dim3(512 / 64, K1 / 64), dim3(256), 0, stream>>>(W1, w1t, K1, 512);
  k_tr<<<dim3(512 / 64, 512 / 64), dim3(256), 0, stream>>>(W2, w2t, 512, 512);
  k_tr<<<dim3(H3 / 64, 512 / 64), dim3(256), 0, stream>>>(W3, w3t, 512, H3);
  k_tr<<<dim3(Npad2 / 64, H3 / 64), dim3(256), 0, stream>>>(W4, w4t, H3, V);

  k_cmag<<<dim3(Cc), dim3(256), 0, stream>>>(cre, cim, cmagT, yn);
  k_mag<<<dim3(M), dim3(256), 0, stream>>>(sre, simg, mag, xcatb, xn);
  k_dots<<<dim3((Cc + 63) / 64, M / 64), dim3(256), 0, stream>>>(mag, cmagT, simsb, M, Cc, D, Cc, xn, yn);
  k_topk<<<dim3(M / 4), dim3(256), 0, stream>>>(simsb, top_sims, top_idx);

  gemm_mfma_bt<<<dim3(512 / 128, M / 128), dim3(256), 0, stream>>>(xcatb, w1t, h1b, M, 512, K1, 512, b1);
  gemm_mfma_bt<<<dim3(512 / 128, M / 128), dim3(256), 0, stream>>>(h1b, w2t, h2b, M, 512, 512, 512, b2);
  gemm_mfma_bt<<<dim3(H3 / 128, M / 128), dim3(256), 0, stream>>>(h2b, w3t, h3b, M, H3, 512, H3, b3);

  gemm_mfma8<<<dim3(256), dim3(512), 0, stream>>>(h3b, w4t, logits, b4);
}

// Round 8
// 492.290 us; speedup vs baseline: 1.0277x; 1.0277x over previous
//
#include <hip/hip_runtime.h>
#include <hip/hip_bf16.h>

#define CEPS 1e-8f

typedef __attribute__((ext_vector_type(8))) __bf16 bf16x8;
typedef __attribute__((ext_vector_type(4))) float f32x4;

__device__ __forceinline__ void gload_lds16(const void* g, void* l) {
  __builtin_amdgcn_global_load_lds((const __attribute__((address_space(1))) unsigned int*)g,
                                   (__attribute__((address_space(3))) unsigned int*)l, 16, 0, 0);
}

__device__ __forceinline__ float gelu_f(float v) {
  return 0.5f * v * (1.0f + erff(v * 0.70710678118654752f));
}

// ---------- magnitude + concat(bf16) + row norm ----------
__global__ __launch_bounds__(256) void k_mag(const float* __restrict__ re, const float* __restrict__ im,
                                             float* __restrict__ mag, __hip_bfloat16* __restrict__ xcat,
                                             float* __restrict__ xn) {
  int row = blockIdx.x;  // 0..2047
  const float* r = re + (size_t)row * 512;
  const float* q = im + (size_t)row * 512;
  double ss = 0.0;
  for (int d = threadIdx.x; d < 512; d += 256) {
    float a = r[d], b = q[d];
    float s = __fadd_rn(__fmul_rn(a, a), __fmul_rn(b, b));  // match np rounding
    float m = __fsqrt_rn(s);
    mag[(size_t)row * 512 + d] = m;
    xcat[(size_t)row * 1024 + d] = __float2bfloat16(a);
    xcat[(size_t)row * 1024 + 512 + d] = __float2bfloat16(b);
    ss += (double)m * (double)m;
  }
  for (int off = 32; off; off >>= 1) ss += __shfl_xor(ss, off);
  __shared__ double red[4];
  int lane = threadIdx.x & 63, wave = threadIdx.x >> 6;
  if (lane == 0) red[wave] = ss;
  __syncthreads();
  if (threadIdx.x == 0) {
    double tot = red[0] + red[1] + red[2] + red[3];
    float n = (float)sqrt(tot);
    xn[row] = fmaxf(n, CEPS);
  }
}

// ---------- concept magnitude (transposed) + norms ----------
__global__ __launch_bounds__(256) void k_cmag(const float* __restrict__ cre, const float* __restrict__ cim,
                                              float* __restrict__ cmagT, float* __restrict__ yn) {
  int c = blockIdx.x;  // 0..999
  const float* r = cre + (size_t)c * 512;
  const float* q = cim + (size_t)c * 512;
  double ss = 0.0;
  for (int d = threadIdx.x; d < 512; d += 256) {
    float a = r[d], b = q[d];
    float s = __fadd_rn(__fmul_rn(a, a), __fmul_rn(b, b));
    float m = __fsqrt_rn(s);
    cmagT[(size_t)d * 1000 + c] = m;
    ss += (double)m * (double)m;
  }
  for (int off = 32; off; off >>= 1) ss += __shfl_xor(ss, off);
  __shared__ double red[4];
  int lane = threadIdx.x & 63, wave = threadIdx.x >> 6;
  if (lane == 0) red[wave] = ss;
  __syncthreads();
  if (threadIdx.x == 0) {
    double tot = red[0] + red[1] + red[2] + red[3];
    float n = (float)sqrt(tot);
    yn[c] = fmaxf(n, CEPS);
  }
}

// ---------- dots GEMM, f64 accumulation; inputs converted to f64 ONCE in LDS (exact) ----------
__global__ __launch_bounds__(256) void k_dots(const float* __restrict__ A, const float* __restrict__ Bm,
                                              float* __restrict__ Cm, int M, int N, int K, int ldc,
                                              const float* __restrict__ xn, const float* __restrict__ yn) {
  __shared__ double As[16][64];
  __shared__ double Bs[16][64];
  const int tid = threadIdx.x;
  const int m0 = blockIdx.y * 64, n0 = blockIdx.x * 64;
  const int tx = tid & 15, ty = tid >> 4;
  const int ar = tid >> 2, ak = (tid & 3) << 2;
  const int bk = tid >> 4, bn = (tid & 15) << 2;
  double acc[4][4] = {};
  for (int k0 = 0; k0 < K; k0 += 16) {
    float4 a4 = *(const float4*)(A + (size_t)(m0 + ar) * K + k0 + ak);
    As[ak + 0][ar] = (double)a4.x; As[ak + 1][ar] = (double)a4.y;
    As[ak + 2][ar] = (double)a4.z; As[ak + 3][ar] = (double)a4.w;
    float4 b4 = make_float4(0.f, 0.f, 0.f, 0.f);
    if (n0 + bn < N) b4 = *(const float4*)(Bm + (size_t)(k0 + bk) * N + n0 + bn);
    Bs[bk][bn + 0] = (double)b4.x; Bs[bk][bn + 1] = (double)b4.y;
    Bs[bk][bn + 2] = (double)b4.z; Bs[bk][bn + 3] = (double)b4.w;
    __syncthreads();
#pragma unroll
    for (int kk = 0; kk < 16; ++kk) {
      double av[4], bv[4];
#pragma unroll
      for (int i = 0; i < 4; ++i) av[i] = As[kk][ty * 4 + i];
#pragma unroll
      for (int j = 0; j < 4; ++j) bv[j] = Bs[kk][tx * 4 + j];
#pragma unroll
      for (int i = 0; i < 4; ++i)
#pragma unroll
        for (int j = 0; j < 4; ++j)
          acc[i][j] = fma(av[i], bv[j], acc[i][j]);
    }
    __syncthreads();
  }
#pragma unroll
  for (int i = 0; i < 4; ++i) {
    int row = m0 + ty * 4 + i;
#pragma unroll
    for (int j = 0; j < 4; ++j) {
      int col = n0 + tx * 4 + j;
      if (col >= N) continue;
      double d = acc[i][j] / ((double)xn[row] * (double)yn[col]);
      Cm[(size_t)row * ldc + col] = (float)d;
    }
  }
}

// ---------- top-5 per row (one wave per row) ----------
__global__ __launch_bounds__(256) void k_topk(const float* __restrict__ sims,
                                              float* __restrict__ top_sims, float* __restrict__ top_idx) {
  int lane = threadIdx.x & 63, wave = threadIdx.x >> 6;
  int row = blockIdx.x * 4 + wave;
  const float* s = sims + (size_t)row * 1000;
  float v[16];
  int idx[16];
#pragma unroll
  for (int t = 0; t < 16; ++t) {
    int c = lane + t * 64;
    if (c < 1000) { v[t] = s[c]; idx[t] = c; }
    else { v[t] = -1e30f; idx[t] = 1 << 20; }
  }
  for (int j = 0; j < 5; ++j) {
    float bv = -1e30f; int bi = 1 << 20;
#pragma unroll
    for (int t = 0; t < 16; ++t) {
      if (v[t] > bv || (v[t] == bv && idx[t] < bi)) { bv = v[t]; bi = idx[t]; }
    }
    float rv = bv; int ri = bi;
#pragma unroll
    for (int off = 32; off; off >>= 1) {
      float ov = __shfl_xor(rv, off);
      int oi = __shfl_xor(ri, off);
      if (ov > rv || (ov == rv && oi < ri)) { rv = ov; ri = oi; }
    }
    if (lane == 0) {
      top_sims[(size_t)row * 5 + j] = rv;
      top_idx[(size_t)row * 5 + j] = (float)ri;
    }
#pragma unroll
    for (int t = 0; t < 16; ++t)
      if (idx[t] == ri) v[t] = -1e30f;
  }
}

// ---------- generic transpose + bf16 convert: W[K,N] f32 -> Wt[Nout rows][K] bf16 (zero-pad n>=N) ----------
__global__ __launch_bounds__(256) void k_tr(const float* __restrict__ W, __hip_bfloat16* __restrict__ Wt,
                                            int K, int N) {
  __shared__ float t32[64][65];
  int n0 = blockIdx.x * 64, k0 = blockIdx.y * 64;
  int tid = threadIdx.x;
  {
    int nc = tid & 15, kr4 = tid >> 4;
#pragma unroll
    for (int p = 0; p < 4; ++p) {
      int kr = p * 16 + kr4;
      int n = n0 + nc * 4;
      float4 v = make_float4(0.f, 0.f, 0.f, 0.f);
      if (n < N) v = *(const float4*)(W + (size_t)(k0 + kr) * N + n);
      t32[kr][nc * 4 + 0] = v.x; t32[kr][nc * 4 + 1] = v.y;
      t32[kr][nc * 4 + 2] = v.z; t32[kr][nc * 4 + 3] = v.w;
    }
  }
  __syncthreads();
  {
    int kc = tid & 15, nr4 = tid >> 4;
#pragma unroll
    for (int p = 0; p < 4; ++p) {
      int nr = p * 16 + nr4;
      ushort4 o;
      {
        __hip_bfloat16 h0 = __float2bfloat16(t32[kc * 4 + 0][nr]);
        __hip_bfloat16 h1 = __float2bfloat16(t32[kc * 4 + 1][nr]);
        __hip_bfloat16 h2 = __float2bfloat16(t32[kc * 4 + 2][nr]);
        __hip_bfloat16 h3 = __float2bfloat16(t32[kc * 4 + 3][nr]);
        o.x = *(unsigned short*)&h0; o.y = *(unsigned short*)&h1;
        o.z = *(unsigned short*)&h2; o.w = *(unsigned short*)&h3;
      }
      *(ushort4*)((unsigned short*)Wt + (size_t)(n0 + nr) * K + k0 + kc * 4) = o;
    }
  }
}

// ---------- 128x128 bf16 MFMA GEMM with gelu+bf16 epilogue (MLP layers) ----------
__global__ __launch_bounds__(256) void gemm_mfma_bt(const __hip_bfloat16* __restrict__ A,
                                                    const __hip_bfloat16* __restrict__ Bt,
                                                    __hip_bfloat16* __restrict__ C, int M, int N, int K,
                                                    int ldc, const float* __restrict__ bias) {
  __shared__ short Al[128 * 32];
  __shared__ short Bl[128 * 32];
  const int tid = threadIdx.x, lane = tid & 63, wave = tid >> 6;
  const int m0 = blockIdx.y * 128, n0 = blockIdx.x * 128;
  const int wr = wave >> 1, wc = wave & 1;
  f32x4 acc[4][4];
  f32x4 zero4 = {0.f, 0.f, 0.f, 0.f};
#pragma unroll
  for (int i = 0; i < 4; ++i)
#pragma unroll
    for (int j = 0; j < 4; ++j) acc[i][j] = zero4;

  const short* Ag = (const short*)A;
  const short* Bg = (const short*)Bt;
  for (int k0 = 0; k0 < K; k0 += 32) {
#pragma unroll
    for (int s = 0; s < 2; ++s) {
      int seg = wave + s * 4;
      int elem = seg * 512 + lane * 8;
      int row = elem >> 5, kk = elem & 31;
      gload_lds16(Ag + (size_t)(m0 + row) * K + k0 + kk, Al + elem);
      gload_lds16(Bg + (size_t)(n0 + row) * K + k0 + kk, Bl + elem);
    }
    __syncthreads();
    bf16x8 af[4], bfr[4];
    const int fr = lane & 15, fk = (lane >> 4) << 3;
#pragma unroll
    for (int i = 0; i < 4; ++i)
      af[i] = *(const bf16x8*)(Al + (wr * 64 + i * 16 + fr) * 32 + fk);
#pragma unroll
    for (int j = 0; j < 4; ++j)
      bfr[j] = *(const bf16x8*)(Bl + (wc * 64 + j * 16 + fr) * 32 + fk);
#pragma unroll
    for (int i = 0; i < 4; ++i)
#pragma unroll
      for (int j = 0; j < 4; ++j)
        acc[i][j] = __builtin_amdgcn_mfma_f32_16x16x32_bf16(af[i], bfr[j], acc[i][j], 0, 0, 0);
    __syncthreads();
  }
  const int fr = lane & 15, fq = lane >> 4;
#pragma unroll
  for (int j = 0; j < 4; ++j) {
    int col = n0 + wc * 64 + j * 16 + fr;
    if (col >= N) continue;
    float bv = bias[col];
#pragma unroll
    for (int i = 0; i < 4; ++i) {
      int rbase = m0 + wr * 64 + i * 16 + fq * 4;
#pragma unroll
      for (int r = 0; r < 4; ++r)
        C[(size_t)(rbase + r) * ldc + col] = __float2bfloat16(gelu_f(acc[i][j][r] + bv));
    }
  }
}

// ---------- final-layer GEMM: m97-replica, 256Mx128N tile, BK=64, single-buffer 48KB LDS ----------
// 2 blocks/CU (launch_bounds(256,2)): cross-block implicit overlap (m114) hides barrier drains.
// 4 waves 2Mx2N, per-wave 128x64. Swapped-operand MFMA -> float4 C dump (r7-verified).
// XCD-bijective grid: xcd=bid&7 owns ntiles {xcd+8k}, m-inner -> 64 resident blocks/XCD
// share 8 B panels (1.5MB, L2-resident). Plain __syncthreads (compiler drains vmcnt).
__global__ __launch_bounds__(256, 2) void gemm_v8(const __hip_bfloat16* __restrict__ A,
                                                  const __hip_bfloat16* __restrict__ Bt,
                                                  float* __restrict__ C,
                                                  const float* __restrict__ bias) {
  const int Kd = 768, Nd = 50000, ldc = 50000;
  __shared__ short As[256 * 64];  // 32KB
  __shared__ short Bs[128 * 64];  // 16KB
  const int tid = threadIdx.x, lane = tid & 63, wave = tid >> 6;
  const int wm = wave >> 1, wn = wave & 1;

  const int xcd = blockIdx.x & 7, j = blockIdx.x >> 3;  // j 0..391
  const int mt = j & 7;                                  // m-inner
  const int ntile = xcd + 8 * (j >> 3);                  // 49 ntiles per xcd
  const int m0 = mt * 256, n0 = ntile * 128;

  const short* Ag = (const short*)A;
  const short* Bg = (const short*)Bt;

  f32x4 acc[8][4];
  f32x4 z4 = {0.f, 0.f, 0.f, 0.f};
#pragma unroll
  for (int q = 0; q < 8; ++q)
#pragma unroll
    for (int p = 0; p < 4; ++p) acc[q][p] = z4;

  for (int kt = 0; kt < 12; ++kt) {
    const int k0 = kt * 64;
    // stage A: 256x64 (8 gloads/thread), B: 128x64 (4 gloads/thread); XOR-swizzled source
#pragma unroll
    for (int r = 0; r < 8; ++r) {
      int idx = r * 256 + tid;
      int row = idx >> 3;
      int ch = (idx & 7) ^ (row & 7);
      gload_lds16(Ag + (size_t)(m0 + row) * Kd + k0 + ch * 8, &As[row * 64 + (idx & 7) * 8]);
    }
#pragma unroll
    for (int r = 0; r < 4; ++r) {
      int idx = r * 256 + tid;
      int row = idx >> 3;
      int ch = (idx & 7) ^ (row & 7);
      gload_lds16(Bg + (size_t)(n0 + row) * Kd + k0 + ch * 8, &Bs[row * 64 + (idx & 7) * 8]);
    }
    __syncthreads();  // compiler drains vmcnt+lgkm before barrier

    // B fragments: rows wn*64 + p*16 + (lane&15), K-halves kh
    bf16x8 bfr[4][2];
#pragma unroll
    for (int p = 0; p < 4; ++p) {
      int row = wn * 64 + p * 16 + (lane & 15);
#pragma unroll
      for (int kh = 0; kh < 2; ++kh) {
        int ch = (kh * 4 + (lane >> 4)) ^ (row & 7);
        bfr[p][kh] = *(const bf16x8*)(&Bs[row * 64 + ch * 8]);
      }
    }
    // A fragments per q, MFMA swapped: acc holds row=lane&15(M), cols=(lane>>4)*4+r (N)
#pragma unroll
    for (int q = 0; q < 8; ++q) {
      int row = wm * 128 + q * 16 + (lane & 15);
      bf16x8 af[2];
#pragma unroll
      for (int kh = 0; kh < 2; ++kh) {
        int ch = (kh * 4 + (lane >> 4)) ^ (row & 7);
        af[kh] = *(const bf16x8*)(&As[row * 64 + ch * 8]);
      }
#pragma unroll
      for (int kh = 0; kh < 2; ++kh)
#pragma unroll
        for (int p = 0; p < 4; ++p)
          acc[q][p] = __builtin_amdgcn_mfma_f32_16x16x32_bf16(bfr[p][kh], af[kh], acc[q][p], 0, 0, 0);
    }
    __syncthreads();  // protect LDS before next stage
  }

  // epilogue: bias + float4 stores (swapped layout: per lane 1 row, 4 consecutive cols)
  const int colq = (lane >> 4) * 4;
  float4 bias4[4];
#pragma unroll
  for (int p = 0; p < 4; ++p) {
    int colbase = n0 + wn * 64 + p * 16 + colq;
    bias4[p] = (colbase < Nd) ? *(const float4*)(bias + colbase) : make_float4(0.f, 0.f, 0.f, 0.f);
  }
#pragma unroll
  for (int q = 0; q < 8; ++q) {
    int row = m0 + wm * 128 + q * 16 + (lane & 15);
#pragma unroll
    for (int p = 0; p < 4; ++p) {
      int colbase = n0 + wn * 64 + p * 16 + colq;
      if (colbase < Nd) {
        f32x4 v = acc[q][p];
        float4 o = make_float4(v[0] + bias4[p].x, v[1] + bias4[p].y,
                               v[2] + bias4[p].z, v[3] + bias4[p].w);
        *(float4*)(&C[(size_t)row * ldc + colbase]) = o;
      }
    }
  }
}

extern "C" void kernel_launch(void* const* d_in, const int* in_sizes, int n_in,
                              void* d_out, int out_size, void* d_ws, size_t ws_size,
                              hipStream_t stream) {
  const float* sre = (const float*)d_in[0];
  const float* simg = (const float*)d_in[1];
  const float* cre = (const float*)d_in[2];
  const float* cim = (const float*)d_in[3];
  const float* W1 = (const float*)d_in[4];
  const float* b1 = (const float*)d_in[5];
  const float* W2 = (const float*)d_in[6];
  const float* b2 = (const float*)d_in[7];
  const float* W3 = (const float*)d_in[8];
  const float* b3 = (const float*)d_in[9];
  const float* W4 = (const float*)d_in[10];
  const float* b4 = (const float*)d_in[11];

  const int M = 2048, D = 512, Cc = 1000, V = 50000, K1 = 1024, H3 = 768;
  const int Npad2 = 392 * 128;  // 50176

  char* ws = (char*)d_ws;
  size_t off = 0;
  auto alloc = [&](size_t bytes) {
    char* p = ws + off;
    off = (off + bytes + 255) & ~(size_t)255;
    return p;
  };
  __hip_bfloat16* xcatb = (__hip_bfloat16*)alloc((size_t)M * K1 * 2);
  float* mag = (float*)alloc((size_t)M * D * 4);
  float* cmagT = (float*)alloc((size_t)D * Cc * 4);
  float* xn = (float*)alloc((size_t)M * 4);
  float* yn = (float*)alloc((size_t)Cc * 4);
  float* simsb = (float*)alloc((size_t)M * Cc * 4);
  __hip_bfloat16* h1b = (__hip_bfloat16*)alloc((size_t)M * 512 * 2);
  __hip_bfloat16* h2b = (__hip_bfloat16*)alloc((size_t)M * 512 * 2);
  __hip_bfloat16* h3b = (__hip_bfloat16*)alloc((size_t)M * H3 * 2);
  __hip_bfloat16* w1t = (__hip_bfloat16*)alloc((size_t)512 * K1 * 2);
  __hip_bfloat16* w2t = (__hip_bfloat16*)alloc((size_t)512 * 512 * 2);
  __hip_bfloat16* w3t = (__hip_bfloat16*)alloc((size_t)H3 * 512 * 2);
  __hip_bfloat16* w4t = (__hip_bfloat16*)alloc((size_t)Npad2 * H3 * 2);

  float* top_sims = (float*)d_out;
  float* top_idx = (float*)d_out + (size_t)M * 5;
  float* logits = (float*)d_out + (size_t)M * 5 * 2;

  k_tr<<<dim3(512 / 64, K1 / 64), dim3(256), 0, stream>>>(W1, w1t, K1, 512);
  k_tr<<<dim3(512 / 64, 512 / 64), dim3(256), 0, stream>>>(W2, w2t, 512, 512);
  k_tr<<<dim3(H3 / 64, 512 / 64), dim3(256), 0, stream>>>(W3, w3t, 512, H3);
  k_tr<<<dim3(Npad2 / 64, H3 / 64), dim3(256), 0, stream>>>(W4, w4t, H3, V);

  k_cmag<<<dim3(Cc), dim3(256), 0, stream>>>(cre, cim, cmagT, yn);
  k_mag<<<dim3(M), dim3(256), 0, stream>>>(sre, simg, mag, xcatb, xn);
  k_dots<<<dim3((Cc + 63) / 64, M / 64), dim3(256), 0, stream>>>(mag, cmagT, simsb, M, Cc, D, Cc, xn, yn);
  k_topk<<<dim3(M / 4), dim3(256), 0, stream>>>(simsb, top_sims, top_idx);

  gemm_mfma_bt<<<dim3(512 / 128, M / 128), dim3(256), 0, stream>>>(xcatb, w1t, h1b, M, 512, K1, 512, b1);
  gemm_mfma_bt<<<dim3(512 / 128, M / 128), dim3(256), 0, stream>>>(h1b, w2t, h2b, M, 512, 512, 512, b2);
  gemm_mfma_bt<<<dim3(H3 / 128, M / 128), dim3(256), 0, stream>>>(h2b, w3t, h3b, M, H3, 512, H3, b3);

  gemm_v8<<<dim3(8 * 392), dim3(256), 0, stream>>>(h3b, w4t, logits, b4);
}

// Round 9
// 475.226 us; speedup vs baseline: 1.0646x; 1.0359x over previous
//
#include <hip/hip_runtime.h>
#include <hip/hip_bf16.h>
#include <hip/hip_fp8.h>

#define CEPS 1e-8f

typedef __attribute__((ext_vector_type(8))) __bf16 bf16x8;
typedef __attribute__((ext_vector_type(4))) float f32x4;

__device__ __forceinline__ void gload_lds16(const void* g, void* l) {
  __builtin_amdgcn_global_load_lds((const __attribute__((address_space(1))) unsigned int*)g,
                                   (__attribute__((address_space(3))) unsigned int*)l, 16, 0, 0);
}

__device__ __forceinline__ float gelu_f(float v) {
  return 0.5f * v * (1.0f + erff(v * 0.70710678118654752f));
}

__device__ __forceinline__ unsigned char f32_to_e4m3(float v) {
  __hip_fp8_e4m3 t(v);
  return (unsigned char)t.__x;
}

// ---------- magnitude + concat(bf16) + row norm ----------
__global__ __launch_bounds__(256) void k_mag(const float* __restrict__ re, const float* __restrict__ im,
                                             float* __restrict__ mag, __hip_bfloat16* __restrict__ xcat,
                                             float* __restrict__ xn) {
  int row = blockIdx.x;  // 0..2047
  const float* r = re + (size_t)row * 512;
  const float* q = im + (size_t)row * 512;
  double ss = 0.0;
  for (int d = threadIdx.x; d < 512; d += 256) {
    float a = r[d], b = q[d];
    float s = __fadd_rn(__fmul_rn(a, a), __fmul_rn(b, b));  // match np rounding
    float m = __fsqrt_rn(s);
    mag[(size_t)row * 512 + d] = m;
    xcat[(size_t)row * 1024 + d] = __float2bfloat16(a);
    xcat[(size_t)row * 1024 + 512 + d] = __float2bfloat16(b);
    ss += (double)m * (double)m;
  }
  for (int off = 32; off; off >>= 1) ss += __shfl_xor(ss, off);
  __shared__ double red[4];
  int lane = threadIdx.x & 63, wave = threadIdx.x >> 6;
  if (lane == 0) red[wave] = ss;
  __syncthreads();
  if (threadIdx.x == 0) {
    double tot = red[0] + red[1] + red[2] + red[3];
    float n = (float)sqrt(tot);
    xn[row] = fmaxf(n, CEPS);
  }
}

// ---------- concept magnitude (transposed) + norms ----------
__global__ __launch_bounds__(256) void k_cmag(const float* __restrict__ cre, const float* __restrict__ cim,
                                              float* __restrict__ cmagT, float* __restrict__ yn) {
  int c = blockIdx.x;  // 0..999
  const float* r = cre + (size_t)c * 512;
  const float* q = cim + (size_t)c * 512;
  double ss = 0.0;
  for (int d = threadIdx.x; d < 512; d += 256) {
    float a = r[d], b = q[d];
    float s = __fadd_rn(__fmul_rn(a, a), __fmul_rn(b, b));
    float m = __fsqrt_rn(s);
    cmagT[(size_t)d * 1000 + c] = m;
    ss += (double)m * (double)m;
  }
  for (int off = 32; off; off >>= 1) ss += __shfl_xor(ss, off);
  __shared__ double red[4];
  int lane = threadIdx.x & 63, wave = threadIdx.x >> 6;
  if (lane == 0) red[wave] = ss;
  __syncthreads();
  if (threadIdx.x == 0) {
    double tot = red[0] + red[1] + red[2] + red[3];
    float n = (float)sqrt(tot);
    yn[c] = fmaxf(n, CEPS);
  }
}

// ---------- dots GEMM, f64 acc; interleaved thread tiles -> all LDS reads broadcast (0-conflict) ----------
// Per-element FMA k-order identical to prior rounds (bitwise-same sims -> top-k safe).
__global__ __launch_bounds__(256) void k_dots(const float* __restrict__ A, const float* __restrict__ Bm,
                                              float* __restrict__ Cm, int M, int N, int K, int ldc,
                                              const float* __restrict__ xn, const float* __restrict__ yn) {
  __shared__ double As[16][64];
  __shared__ double Bs[16][64];
  const int tid = threadIdx.x;
  const int m0 = blockIdx.y * 64, n0 = blockIdx.x * 64;
  const int tx = tid & 15, ty4 = tid >> 4;  // interleaved: m = ty4 + 16i, n = tx + 16j
  const int ar = tid >> 2, ak = (tid & 3) << 2;
  const int bk = tid >> 4, bn = (tid & 15) << 2;
  double acc[4][4] = {};
  for (int k0 = 0; k0 < K; k0 += 16) {
    float4 a4 = *(const float4*)(A + (size_t)(m0 + ar) * K + k0 + ak);
    As[ak + 0][ar] = (double)a4.x; As[ak + 1][ar] = (double)a4.y;
    As[ak + 2][ar] = (double)a4.z; As[ak + 3][ar] = (double)a4.w;
    float4 b4 = make_float4(0.f, 0.f, 0.f, 0.f);
    if (n0 + bn < N) b4 = *(const float4*)(Bm + (size_t)(k0 + bk) * N + n0 + bn);
    Bs[bk][bn + 0] = (double)b4.x; Bs[bk][bn + 1] = (double)b4.y;
    Bs[bk][bn + 2] = (double)b4.z; Bs[bk][bn + 3] = (double)b4.w;
    __syncthreads();
#pragma unroll
    for (int kk = 0; kk < 16; ++kk) {
      double av[4], bv[4];
#pragma unroll
      for (int i = 0; i < 4; ++i) av[i] = As[kk][ty4 + i * 16];
#pragma unroll
      for (int j = 0; j < 4; ++j) bv[j] = Bs[kk][tx + j * 16];
#pragma unroll
      for (int i = 0; i < 4; ++i)
#pragma unroll
        for (int j = 0; j < 4; ++j)
          acc[i][j] = fma(av[i], bv[j], acc[i][j]);
    }
    __syncthreads();
  }
#pragma unroll
  for (int i = 0; i < 4; ++i) {
    int row = m0 + ty4 + i * 16;
#pragma unroll
    for (int j = 0; j < 4; ++j) {
      int col = n0 + tx + j * 16;
      if (col >= N) continue;
      double d = acc[i][j] / ((double)xn[row] * (double)yn[col]);
      Cm[(size_t)row * ldc + col] = (float)d;
    }
  }
}

// ---------- top-5 per row (one wave per row) ----------
__global__ __launch_bounds__(256) void k_topk(const float* __restrict__ sims,
                                              float* __restrict__ top_sims, float* __restrict__ top_idx) {
  int lane = threadIdx.x & 63, wave = threadIdx.x >> 6;
  int row = blockIdx.x * 4 + wave;
  const float* s = sims + (size_t)row * 1000;
  float v[16];
  int idx[16];
#pragma unroll
  for (int t = 0; t < 16; ++t) {
    int c = lane + t * 64;
    if (c < 1000) { v[t] = s[c]; idx[t] = c; }
    else { v[t] = -1e30f; idx[t] = 1 << 20; }
  }
  for (int j = 0; j < 5; ++j) {
    float bv = -1e30f; int bi = 1 << 20;
#pragma unroll
    for (int t = 0; t < 16; ++t) {
      if (v[t] > bv || (v[t] == bv && idx[t] < bi)) { bv = v[t]; bi = idx[t]; }
    }
    float rv = bv; int ri = bi;
#pragma unroll
    for (int off = 32; off; off >>= 1) {
      float ov = __shfl_xor(rv, off);
      int oi = __shfl_xor(ri, off);
      if (ov > rv || (ov == rv && oi < ri)) { rv = ov; ri = oi; }
    }
    if (lane == 0) {
      top_sims[(size_t)row * 5 + j] = rv;
      top_idx[(size_t)row * 5 + j] = (float)ri;
    }
#pragma unroll
    for (int t = 0; t < 16; ++t)
      if (idx[t] == ri) v[t] = -1e30f;
  }
}

// ---------- transpose: W[K,N] f32 -> Wt[Nout rows][K], OUTT 0=bf16, 1=fp8 (zero-pad n>=N) ----------
template <int OUTT>
__global__ __launch_bounds__(256) void k_tr(const float* __restrict__ W, void* __restrict__ Wt,
                                            int K, int N) {
  __shared__ float t32[64][65];
  int n0 = blockIdx.x * 64, k0 = blockIdx.y * 64;
  int tid = threadIdx.x;
  {
    int nc = tid & 15, kr4 = tid >> 4;
#pragma unroll
    for (int p = 0; p < 4; ++p) {
      int kr = p * 16 + kr4;
      int n = n0 + nc * 4;
      float4 v = make_float4(0.f, 0.f, 0.f, 0.f);
      if (n < N) v = *(const float4*)(W + (size_t)(k0 + kr) * N + n);
      t32[kr][nc * 4 + 0] = v.x; t32[kr][nc * 4 + 1] = v.y;
      t32[kr][nc * 4 + 2] = v.z; t32[kr][nc * 4 + 3] = v.w;
    }
  }
  __syncthreads();
  {
    int kc = tid & 15, nr4 = tid >> 4;
#pragma unroll
    for (int p = 0; p < 4; ++p) {
      int nr = p * 16 + nr4;
      if (OUTT == 0) {
        ushort4 o;
        __hip_bfloat16 h0 = __float2bfloat16(t32[kc * 4 + 0][nr]);
        __hip_bfloat16 h1 = __float2bfloat16(t32[kc * 4 + 1][nr]);
        __hip_bfloat16 h2 = __float2bfloat16(t32[kc * 4 + 2][nr]);
        __hip_bfloat16 h3 = __float2bfloat16(t32[kc * 4 + 3][nr]);
        o.x = *(unsigned short*)&h0; o.y = *(unsigned short*)&h1;
        o.z = *(unsigned short*)&h2; o.w = *(unsigned short*)&h3;
        *(ushort4*)((unsigned short*)Wt + (size_t)(n0 + nr) * K + k0 + kc * 4) = o;
      } else {
        unsigned int o = (unsigned int)f32_to_e4m3(t32[kc * 4 + 0][nr]) |
                         ((unsigned int)f32_to_e4m3(t32[kc * 4 + 1][nr]) << 8) |
                         ((unsigned int)f32_to_e4m3(t32[kc * 4 + 2][nr]) << 16) |
                         ((unsigned int)f32_to_e4m3(t32[kc * 4 + 3][nr]) << 24);
        *(unsigned int*)((unsigned char*)Wt + (size_t)(n0 + nr) * K + k0 + kc * 4) = o;
      }
    }
  }
}

// ---------- 128x128 bf16 MFMA GEMM, gelu epilogue; OUTT 0=bf16 out, 1=fp8 out ----------
template <int OUTT>
__global__ __launch_bounds__(256) void gemm_mfma_bt(const __hip_bfloat16* __restrict__ A,
                                                    const __hip_bfloat16* __restrict__ Bt,
                                                    void* __restrict__ C, int M, int N, int K,
                                                    int ldc, const float* __restrict__ bias) {
  __shared__ short Al[128 * 32];
  __shared__ short Bl[128 * 32];
  const int tid = threadIdx.x, lane = tid & 63, wave = tid >> 6;
  const int m0 = blockIdx.y * 128, n0 = blockIdx.x * 128;
  const int wr = wave >> 1, wc = wave & 1;
  f32x4 acc[4][4];
  f32x4 zero4 = {0.f, 0.f, 0.f, 0.f};
#pragma unroll
  for (int i = 0; i < 4; ++i)
#pragma unroll
    for (int j = 0; j < 4; ++j) acc[i][j] = zero4;

  const short* Ag = (const short*)A;
  const short* Bg = (const short*)Bt;
  for (int k0 = 0; k0 < K; k0 += 32) {
#pragma unroll
    for (int s = 0; s < 2; ++s) {
      int seg = wave + s * 4;
      int elem = seg * 512 + lane * 8;
      int row = elem >> 5, kk = elem & 31;
      gload_lds16(Ag + (size_t)(m0 + row) * K + k0 + kk, Al + elem);
      gload_lds16(Bg + (size_t)(n0 + row) * K + k0 + kk, Bl + elem);
    }
    __syncthreads();
    bf16x8 af[4], bfr[4];
    const int fr = lane & 15, fk = (lane >> 4) << 3;
#pragma unroll
    for (int i = 0; i < 4; ++i)
      af[i] = *(const bf16x8*)(Al + (wr * 64 + i * 16 + fr) * 32 + fk);
#pragma unroll
    for (int j = 0; j < 4; ++j)
      bfr[j] = *(const bf16x8*)(Bl + (wc * 64 + j * 16 + fr) * 32 + fk);
#pragma unroll
    for (int i = 0; i < 4; ++i)
#pragma unroll
      for (int j = 0; j < 4; ++j)
        acc[i][j] = __builtin_amdgcn_mfma_f32_16x16x32_bf16(af[i], bfr[j], acc[i][j], 0, 0, 0);
    __syncthreads();
  }
  const int fr = lane & 15, fq = lane >> 4;
#pragma unroll
  for (int j = 0; j < 4; ++j) {
    int col = n0 + wc * 64 + j * 16 + fr;
    if (col >= N) continue;
    float bv = bias[col];
#pragma unroll
    for (int i = 0; i < 4; ++i) {
      int rbase = m0 + wr * 64 + i * 16 + fq * 4;
#pragma unroll
      for (int r = 0; r < 4; ++r) {
        float v = gelu_f(acc[i][j][r] + bv);
        if (OUTT == 0)
          ((__hip_bfloat16*)C)[(size_t)(rbase + r) * ldc + col] = __float2bfloat16(v);
        else
          ((unsigned char*)C)[(size_t)(rbase + r) * ldc + col] = f32_to_e4m3(v);
      }
    }
  }
}

// ---------- final-layer GEMM: fp8 operands, 256Mx128N tile, BK=64, DOUBLE-buffered 48KB LDS ----------
// fp8 halves tile bytes -> dbuf + 2 blocks/CU both fit (96KB). Counted vmcnt(6) per K-tile
// (vmcnt(0) only on the last) -> staging latency hides behind a full K-tile of compute plus
// the co-resident block. Source-swizzle slot^=(row&6) (16B-granule-safe); frag b64 reads.
// Swapped-operand MFMA -> float4 C dump (r7-verified layout).
__global__ __launch_bounds__(256, 2) void gemm_v9(const unsigned char* __restrict__ A8,
                                                  const unsigned char* __restrict__ B8,
                                                  float* __restrict__ C,
                                                  const float* __restrict__ bias) {
  const int KNT = 12;  // K/64
  const int Kd = 768, Nd = 50000, ldc = 50000;
  __shared__ unsigned char As[2][256 * 64];  // 16KB each
  __shared__ unsigned char Bs[2][128 * 64];  // 8KB each
  const int tid = threadIdx.x, lane = tid & 63, wave = tid >> 6;
  const int wm = wave >> 1, wn = wave & 1;

  const int xcd = blockIdx.x & 7, j = blockIdx.x >> 3;  // j 0..391
  const int mt = j & 7;
  const int ntile = xcd + 8 * (j >> 3);
  const int m0 = mt * 256, n0 = ntile * 128;

  f32x4 acc[8][4];
  f32x4 z4 = {0.f, 0.f, 0.f, 0.f};
#pragma unroll
  for (int q = 0; q < 8; ++q)
#pragma unroll
    for (int p = 0; p < 4; ++p) acc[q][p] = z4;

  // stage K-tile kt into buf: A 4 gloads/thread, B 2 gloads/thread (6 VMEM/wave/tile)
  auto stageA = [&](int kt, int buf) {
    if (kt >= KNT) return;
    const int k0 = kt * 64;
#pragma unroll
    for (int r = 0; r < 4; ++r) {
      int idx = r * 256 + tid;           // 0..1023 16B-chunks
      int row = idx >> 2, c = idx & 3;
      int src = ((c * 2) ^ (row & 6)) * 8;  // 16B-contiguous since (row&6) even
      gload_lds16(A8 + (size_t)(m0 + row) * Kd + k0 + src, &As[buf][row * 64 + c * 16]);
    }
  };
  auto stageB = [&](int kt, int buf) {
    if (kt >= KNT) return;
    const int k0 = kt * 64;
#pragma unroll
    for (int r = 0; r < 2; ++r) {
      int idx = r * 256 + tid;           // 0..511
      int row = idx >> 2, c = idx & 3;
      int src = ((c * 2) ^ (row & 6)) * 8;
      gload_lds16(B8 + (size_t)(n0 + row) * Kd + k0 + src, &Bs[buf][row * 64 + c * 16]);
    }
  };

  // prologue: tiles 0 and 1 staged into buf0/buf1
  stageA(0, 0); stageB(0, 0);
  stageA(1, 1); stageB(1, 1);

  for (int g = 0; g < KNT; ++g) {
    const int buf = g & 1;
    if (g < KNT - 1) asm volatile("s_waitcnt vmcnt(6)" ::: "memory");  // tile g landed, g+1 in flight
    else             asm volatile("s_waitcnt vmcnt(0)" ::: "memory");
    __builtin_amdgcn_sched_barrier(0);
    __builtin_amdgcn_s_barrier();
    __builtin_amdgcn_sched_barrier(0);

    // B fragments: slot s holds global kchunk s^(row&6)
    long bfr[4][2];
#pragma unroll
    for (int p = 0; p < 4; ++p) {
      int row = wn * 64 + p * 16 + (lane & 15);
#pragma unroll
      for (int kh = 0; kh < 2; ++kh) {
        int slot = (kh * 4 + (lane >> 4)) ^ (row & 6);
        bfr[p][kh] = *(const long*)(&Bs[buf][row * 64 + slot * 8]);
      }
    }
#pragma unroll
    for (int q = 0; q < 8; ++q) {
      int rowA = wm * 128 + q * 16 + (lane & 15);
      long af[2];
#pragma unroll
      for (int kh = 0; kh < 2; ++kh) {
        int slot = (kh * 4 + (lane >> 4)) ^ (rowA & 6);
        af[kh] = *(const long*)(&As[buf][rowA * 64 + slot * 8]);
      }
#pragma unroll
      for (int kh = 0; kh < 2; ++kh)
#pragma unroll
        for (int p = 0; p < 4; ++p)
          acc[q][p] = __builtin_amdgcn_mfma_f32_16x16x32_fp8_fp8(bfr[p][kh], af[kh], acc[q][p], 0, 0, 0);
    }

    __builtin_amdgcn_sched_barrier(0);
    __builtin_amdgcn_s_barrier();
    __builtin_amdgcn_sched_barrier(0);
    // stage tile g+2 into the buffer just freed (all waves past the barrier)
    stageA(g + 2, buf);
    stageB(g + 2, buf);
  }

  // epilogue: bias + float4 stores (swapped layout: per lane 1 row, 4 consecutive cols)
  const int colq = (lane >> 4) * 4;
  float4 bias4[4];
#pragma unroll
  for (int p = 0; p < 4; ++p) {
    int colbase = n0 + wn * 64 + p * 16 + colq;
    bias4[p] = (colbase < Nd) ? *(const float4*)(bias + colbase) : make_float4(0.f, 0.f, 0.f, 0.f);
  }
#pragma unroll
  for (int q = 0; q < 8; ++q) {
    int row = m0 + wm * 128 + q * 16 + (lane & 15);
#pragma unroll
    for (int p = 0; p < 4; ++p) {
      int colbase = n0 + wn * 64 + p * 16 + colq;
      if (colbase < Nd) {
        f32x4 v = acc[q][p];
        float4 o = make_float4(v[0] + bias4[p].x, v[1] + bias4[p].y,
                               v[2] + bias4[p].z, v[3] + bias4[p].w);
        *(float4*)(&C[(size_t)row * ldc + colbase]) = o;
      }
    }
  }
}

extern "C" void kernel_launch(void* const* d_in, const int* in_sizes, int n_in,
                              void* d_out, int out_size, void* d_ws, size_t ws_size,
                              hipStream_t stream) {
  const float* sre = (const float*)d_in[0];
  const float* simg = (const float*)d_in[1];
  const float* cre = (const float*)d_in[2];
  const float* cim = (const float*)d_in[3];
  const float* W1 = (const float*)d_in[4];
  const float* b1 = (const float*)d_in[5];
  const float* W2 = (const float*)d_in[6];
  const float* b2 = (const float*)d_in[7];
  const float* W3 = (const float*)d_in[8];
  const float* b3 = (const float*)d_in[9];
  const float* W4 = (const float*)d_in[10];
  const float* b4 = (const float*)d_in[11];

  const int M = 2048, D = 512, Cc = 1000, V = 50000, K1 = 1024, H3 = 768;
  const int Npad2 = 392 * 128;  // 50176

  char* ws = (char*)d_ws;
  size_t off = 0;
  auto alloc = [&](size_t bytes) {
    char* p = ws + off;
    off = (off + bytes + 255) & ~(size_t)255;
    return p;
  };
  __hip_bfloat16* xcatb = (__hip_bfloat16*)alloc((size_t)M * K1 * 2);
  float* mag = (float*)alloc((size_t)M * D * 4);
  float* cmagT = (float*)alloc((size_t)D * Cc * 4);
  float* xn = (float*)alloc((size_t)M * 4);
  float* yn = (float*)alloc((size_t)Cc * 4);
  float* simsb = (float*)alloc((size_t)M * Cc * 4);
  __hip_bfloat16* h1b = (__hip_bfloat16*)alloc((size_t)M * 512 * 2);
  __hip_bfloat16* h2b = (__hip_bfloat16*)alloc((size_t)M * 512 * 2);
  unsigned char* h3f8 = (unsigned char*)alloc((size_t)M * H3);
  __hip_bfloat16* w1t = (__hip_bfloat16*)alloc((size_t)512 * K1 * 2);
  __hip_bfloat16* w2t = (__hip_bfloat16*)alloc((size_t)512 * 512 * 2);
  __hip_bfloat16* w3t = (__hip_bfloat16*)alloc((size_t)H3 * 512 * 2);
  unsigned char* w4f8 = (unsigned char*)alloc((size_t)Npad2 * H3);

  float* top_sims = (float*)d_out;
  float* top_idx = (float*)d_out + (size_t)M * 5;
  float* logits = (float*)d_out + (size_t)M * 5 * 2;

  k_tr<0><<<dim3(512 / 64, K1 / 64), dim3(256), 0, stream>>>(W1, (void*)w1t, K1, 512);
  k_tr<0><<<dim3(512 / 64, 512 / 64), dim3(256), 0, stream>>>(W2, (void*)w2t, 512, 512);
  k_tr<0><<<dim3(H3 / 64, 512 / 64), dim3(256), 0, stream>>>(W3, (void*)w3t, 512, H3);
  k_tr<1><<<dim3(Npad2 / 64, H3 / 64), dim3(256), 0, stream>>>(W4, (void*)w4f8, H3, V);

  k_cmag<<<dim3(Cc), dim3(256), 0, stream>>>(cre, cim, cmagT, yn);
  k_mag<<<dim3(M), dim3(256), 0, stream>>>(sre, simg, mag, xcatb, xn);
  k_dots<<<dim3((Cc + 63) / 64, M / 64), dim3(256), 0, stream>>>(mag, cmagT, simsb, M, Cc, D, Cc, xn, yn);
  k_topk<<<dim3(M / 4), dim3(256), 0, stream>>>(simsb, top_sims, top_idx);

  gemm_mfma_bt<0><<<dim3(512 / 128, M / 128), dim3(256), 0, stream>>>(xcatb, w1t, (void*)h1b, M, 512, K1, 512, b1);
  gemm_mfma_bt<0><<<dim3(512 / 128, M / 128), dim3(256), 0, stream>>>(h1b, w2t, (void*)h2b, M, 512, 512, 512, b2);
  gemm_mfma_bt<1><<<dim3(H3 / 128, M / 128), dim3(256), 0, stream>>>(h2b, w3t, (void*)h3f8, M, H3, 512, H3, b3);

  gemm_v9<<<dim3(8 * 392), dim3(256), 0, stream>>>(h3f8, w4f8, logits, b4);
}

// Round 10
// 407.174 us; speedup vs baseline: 1.2425x; 1.1671x over previous
//
#include <hip/hip_runtime.h>
#include <hip/hip_bf16.h>
#include <hip/hip_fp8.h>

#define CEPS 1e-8f

typedef __attribute__((ext_vector_type(8))) __bf16 bf16x8;
typedef __attribute__((ext_vector_type(4))) float f32x4;

__device__ __forceinline__ void gload_lds16(const void* g, void* l) {
  __builtin_amdgcn_global_load_lds((const __attribute__((address_space(1))) unsigned int*)g,
                                   (__attribute__((address_space(3))) unsigned int*)l, 16, 0, 0);
}

__device__ __forceinline__ float gelu_f(float v) {
  return 0.5f * v * (1.0f + erff(v * 0.70710678118654752f));
}

__device__ __forceinline__ unsigned char f32_to_e4m3(float v) {
  __hip_fp8_e4m3 t(v);
  return (unsigned char)t.__x;
}

// ================= device bodies (byte-equivalent to round-9 kernels) =================

// ---- magnitude + concat(bf16) + row norm ----
__device__ __forceinline__ void dev_mag(double* red, const float* __restrict__ re,
                                        const float* __restrict__ im, float* __restrict__ mag,
                                        __hip_bfloat16* __restrict__ xcat, float* __restrict__ xn,
                                        int row) {
  const float* r = re + (size_t)row * 512;
  const float* q = im + (size_t)row * 512;
  double ss = 0.0;
  for (int d = threadIdx.x; d < 512; d += 256) {
    float a = r[d], b = q[d];
    float s = __fadd_rn(__fmul_rn(a, a), __fmul_rn(b, b));  // match np rounding
    float m = __fsqrt_rn(s);
    mag[(size_t)row * 512 + d] = m;
    xcat[(size_t)row * 1024 + d] = __float2bfloat16(a);
    xcat[(size_t)row * 1024 + 512 + d] = __float2bfloat16(b);
    ss += (double)m * (double)m;
  }
  for (int off = 32; off; off >>= 1) ss += __shfl_xor(ss, off);
  int lane = threadIdx.x & 63, wave = threadIdx.x >> 6;
  if (lane == 0) red[wave] = ss;
  __syncthreads();
  if (threadIdx.x == 0) {
    double tot = red[0] + red[1] + red[2] + red[3];
    float n = (float)sqrt(tot);
    xn[row] = fmaxf(n, CEPS);
  }
}

// ---- concept magnitude (transposed) + norms ----
__device__ __forceinline__ void dev_cmag(double* red, const float* __restrict__ cre,
                                         const float* __restrict__ cim, float* __restrict__ cmagT,
                                         float* __restrict__ yn, int c) {
  const float* r = cre + (size_t)c * 512;
  const float* q = cim + (size_t)c * 512;
  double ss = 0.0;
  for (int d = threadIdx.x; d < 512; d += 256) {
    float a = r[d], b = q[d];
    float s = __fadd_rn(__fmul_rn(a, a), __fmul_rn(b, b));
    float m = __fsqrt_rn(s);
    cmagT[(size_t)d * 1000 + c] = m;
    ss += (double)m * (double)m;
  }
  for (int off = 32; off; off >>= 1) ss += __shfl_xor(ss, off);
  int lane = threadIdx.x & 63, wave = threadIdx.x >> 6;
  if (lane == 0) red[wave] = ss;
  __syncthreads();
  if (threadIdx.x == 0) {
    double tot = red[0] + red[1] + red[2] + red[3];
    float n = (float)sqrt(tot);
    yn[c] = fmaxf(n, CEPS);
  }
}

// ---- transpose: W[K,N] f32 -> Wt[n][k] (OUTT 0=bf16, 1=fp8; zero-pad n>=N) ----
template <int OUTT>
__device__ __forceinline__ void dev_tr(float (*t32)[65], const float* __restrict__ W,
                                       void* __restrict__ Wt, int K, int N, int bx, int by) {
  int n0 = bx * 64, k0 = by * 64;
  int tid = threadIdx.x;
  {
    int nc = tid & 15, kr4 = tid >> 4;
#pragma unroll
    for (int p = 0; p < 4; ++p) {
      int kr = p * 16 + kr4;
      int n = n0 + nc * 4;
      float4 v = make_float4(0.f, 0.f, 0.f, 0.f);
      if (n < N) v = *(const float4*)(W + (size_t)(k0 + kr) * N + n);
      t32[kr][nc * 4 + 0] = v.x; t32[kr][nc * 4 + 1] = v.y;
      t32[kr][nc * 4 + 2] = v.z; t32[kr][nc * 4 + 3] = v.w;
    }
  }
  __syncthreads();
  {
    int kc = tid & 15, nr4 = tid >> 4;
#pragma unroll
    for (int p = 0; p < 4; ++p) {
      int nr = p * 16 + nr4;
      if (OUTT == 0) {
        ushort4 o;
        __hip_bfloat16 h0 = __float2bfloat16(t32[kc * 4 + 0][nr]);
        __hip_bfloat16 h1 = __float2bfloat16(t32[kc * 4 + 1][nr]);
        __hip_bfloat16 h2 = __float2bfloat16(t32[kc * 4 + 2][nr]);
        __hip_bfloat16 h3 = __float2bfloat16(t32[kc * 4 + 3][nr]);
        o.x = *(unsigned short*)&h0; o.y = *(unsigned short*)&h1;
        o.z = *(unsigned short*)&h2; o.w = *(unsigned short*)&h3;
        *(ushort4*)((unsigned short*)Wt + (size_t)(n0 + nr) * K + k0 + kc * 4) = o;
      } else {
        unsigned int o = (unsigned int)f32_to_e4m3(t32[kc * 4 + 0][nr]) |
                         ((unsigned int)f32_to_e4m3(t32[kc * 4 + 1][nr]) << 8) |
                         ((unsigned int)f32_to_e4m3(t32[kc * 4 + 2][nr]) << 16) |
                         ((unsigned int)f32_to_e4m3(t32[kc * 4 + 3][nr]) << 24);
        *(unsigned int*)((unsigned char*)Wt + (size_t)(n0 + nr) * K + k0 + kc * 4) = o;
      }
    }
  }
}

// ---- 128x128 bf16 MFMA GEMM with gelu epilogue (MLP layers) ----
template <int OUTT>
__device__ __forceinline__ void dev_mlp(short* Al, short* Bl, const __hip_bfloat16* __restrict__ A,
                                        const __hip_bfloat16* __restrict__ Bt, void* __restrict__ C,
                                        int M, int N, int K, int ldc, const float* __restrict__ bias,
                                        int bx, int by) {
  const int tid = threadIdx.x, lane = tid & 63, wave = tid >> 6;
  const int m0 = by * 128, n0 = bx * 128;
  const int wr = wave >> 1, wc = wave & 1;
  f32x4 acc[4][4];
  f32x4 zero4 = {0.f, 0.f, 0.f, 0.f};
#pragma unroll
  for (int i = 0; i < 4; ++i)
#pragma unroll
    for (int j = 0; j < 4; ++j) acc[i][j] = zero4;

  const short* Ag = (const short*)A;
  const short* Bg = (const short*)Bt;
  for (int k0 = 0; k0 < K; k0 += 32) {
#pragma unroll
    for (int s = 0; s < 2; ++s) {
      int seg = wave + s * 4;
      int elem = seg * 512 + lane * 8;
      int row = elem >> 5, kk = elem & 31;
      gload_lds16(Ag + (size_t)(m0 + row) * K + k0 + kk, Al + elem);
      gload_lds16(Bg + (size_t)(n0 + row) * K + k0 + kk, Bl + elem);
    }
    __syncthreads();
    bf16x8 af[4], bfr[4];
    const int fr = lane & 15, fk = (lane >> 4) << 3;
#pragma unroll
    for (int i = 0; i < 4; ++i)
      af[i] = *(const bf16x8*)(Al + (wr * 64 + i * 16 + fr) * 32 + fk);
#pragma unroll
    for (int j = 0; j < 4; ++j)
      bfr[j] = *(const bf16x8*)(Bl + (wc * 64 + j * 16 + fr) * 32 + fk);
#pragma unroll
    for (int i = 0; i < 4; ++i)
#pragma unroll
      for (int j = 0; j < 4; ++j)
        acc[i][j] = __builtin_amdgcn_mfma_f32_16x16x32_bf16(af[i], bfr[j], acc[i][j], 0, 0, 0);
    __syncthreads();
  }
  const int fr = lane & 15, fq = lane >> 4;
#pragma unroll
  for (int j = 0; j < 4; ++j) {
    int col = n0 + wc * 64 + j * 16 + fr;
    if (col >= N) continue;
    float bv = bias[col];
#pragma unroll
    for (int i = 0; i < 4; ++i) {
      int rbase = m0 + wr * 64 + i * 16 + fq * 4;
#pragma unroll
      for (int r = 0; r < 4; ++r) {
        float v = gelu_f(acc[i][j][r] + bv);
        if (OUTT == 0)
          ((__hip_bfloat16*)C)[(size_t)(rbase + r) * ldc + col] = __float2bfloat16(v);
        else
          ((unsigned char*)C)[(size_t)(rbase + r) * ldc + col] = f32_to_e4m3(v);
      }
    }
  }
}

// ---- dots GEMM, f64 acc, interleaved broadcast reads (bitwise-same sims as round 9) ----
__device__ __forceinline__ void dev_dots(double (*As)[64], double (*Bs)[64],
                                         const float* __restrict__ A, const float* __restrict__ Bm,
                                         float* __restrict__ Cm, int M, int N, int K, int ldc,
                                         const float* __restrict__ xn, const float* __restrict__ yn,
                                         int nb, int mb) {
  const int tid = threadIdx.x;
  const int m0 = mb * 64, n0 = nb * 64;
  const int tx = tid & 15, ty4 = tid >> 4;
  const int ar = tid >> 2, ak = (tid & 3) << 2;
  const int bk = tid >> 4, bn = (tid & 15) << 2;
  double acc[4][4] = {};
  for (int k0 = 0; k0 < K; k0 += 16) {
    float4 a4 = *(const float4*)(A + (size_t)(m0 + ar) * K + k0 + ak);
    As[ak + 0][ar] = (double)a4.x; As[ak + 1][ar] = (double)a4.y;
    As[ak + 2][ar] = (double)a4.z; As[ak + 3][ar] = (double)a4.w;
    float4 b4 = make_float4(0.f, 0.f, 0.f, 0.f);
    if (n0 + bn < N) b4 = *(const float4*)(Bm + (size_t)(k0 + bk) * N + n0 + bn);
    Bs[bk][bn + 0] = (double)b4.x; Bs[bk][bn + 1] = (double)b4.y;
    Bs[bk][bn + 2] = (double)b4.z; Bs[bk][bn + 3] = (double)b4.w;
    __syncthreads();
#pragma unroll
    for (int kk = 0; kk < 16; ++kk) {
      double av[4], bv[4];
#pragma unroll
      for (int i = 0; i < 4; ++i) av[i] = As[kk][ty4 + i * 16];
#pragma unroll
      for (int j = 0; j < 4; ++j) bv[j] = Bs[kk][tx + j * 16];
#pragma unroll
      for (int i = 0; i < 4; ++i)
#pragma unroll
        for (int j = 0; j < 4; ++j)
          acc[i][j] = fma(av[i], bv[j], acc[i][j]);
    }
    __syncthreads();
  }
#pragma unroll
  for (int i = 0; i < 4; ++i) {
    int row = m0 + ty4 + i * 16;
#pragma unroll
    for (int j = 0; j < 4; ++j) {
      int col = n0 + tx + j * 16;
      if (col >= N) continue;
      double d = acc[i][j] / ((double)xn[row] * (double)yn[col]);
      Cm[(size_t)row * ldc + col] = (float)d;
    }
  }
}

// ---- final-layer fp8 GEMM body (round-9 gemm_v9, + setprio around MFMA) ----
__device__ __forceinline__ void dev_gemm(unsigned char (*As)[16384], unsigned char (*Bs)[8192],
                                         const unsigned char* __restrict__ A8,
                                         const unsigned char* __restrict__ B8,
                                         float* __restrict__ C, const float* __restrict__ bias,
                                         int xcd, int j) {
  const int KNT = 12;
  const int Kd = 768, Nd = 50000, ldc = 50000;
  const int tid = threadIdx.x, lane = tid & 63, wave = tid >> 6;
  const int wm = wave >> 1, wn = wave & 1;

  const int mt = j & 7;
  const int ntile = xcd + 8 * (j >> 3);
  const int m0 = mt * 256, n0 = ntile * 128;

  f32x4 acc[8][4];
  f32x4 z4 = {0.f, 0.f, 0.f, 0.f};
#pragma unroll
  for (int q = 0; q < 8; ++q)
#pragma unroll
    for (int p = 0; p < 4; ++p) acc[q][p] = z4;

  auto stageA = [&](int kt, int buf) {
    if (kt >= KNT) return;
    const int k0 = kt * 64;
#pragma unroll
    for (int r = 0; r < 4; ++r) {
      int idx = r * 256 + tid;
      int row = idx >> 2, c = idx & 3;
      int src = ((c * 2) ^ (row & 6)) * 8;
      gload_lds16(A8 + (size_t)(m0 + row) * Kd + k0 + src, &As[buf][row * 64 + c * 16]);
    }
  };
  auto stageB = [&](int kt, int buf) {
    if (kt >= KNT) return;
    const int k0 = kt * 64;
#pragma unroll
    for (int r = 0; r < 2; ++r) {
      int idx = r * 256 + tid;
      int row = idx >> 2, c = idx & 3;
      int src = ((c * 2) ^ (row & 6)) * 8;
      gload_lds16(B8 + (size_t)(n0 + row) * Kd + k0 + src, &Bs[buf][row * 64 + c * 16]);
    }
  };

  stageA(0, 0); stageB(0, 0);
  stageA(1, 1); stageB(1, 1);

  for (int g = 0; g < KNT; ++g) {
    const int buf = g & 1;
    if (g < KNT - 1) asm volatile("s_waitcnt vmcnt(6)" ::: "memory");
    else             asm volatile("s_waitcnt vmcnt(0)" ::: "memory");
    __builtin_amdgcn_sched_barrier(0);
    __builtin_amdgcn_s_barrier();
    __builtin_amdgcn_sched_barrier(0);

    long bfr[4][2];
#pragma unroll
    for (int p = 0; p < 4; ++p) {
      int row = wn * 64 + p * 16 + (lane & 15);
#pragma unroll
      for (int kh = 0; kh < 2; ++kh) {
        int slot = (kh * 4 + (lane >> 4)) ^ (row & 6);
        bfr[p][kh] = *(const long*)(&Bs[buf][row * 64 + slot * 8]);
      }
    }
    __builtin_amdgcn_s_setprio(1);
#pragma unroll
    for (int q = 0; q < 8; ++q) {
      int rowA = wm * 128 + q * 16 + (lane & 15);
      long af[2];
#pragma unroll
      for (int kh = 0; kh < 2; ++kh) {
        int slot = (kh * 4 + (lane >> 4)) ^ (rowA & 6);
        af[kh] = *(const long*)(&As[buf][rowA * 64 + slot * 8]);
      }
#pragma unroll
      for (int kh = 0; kh < 2; ++kh)
#pragma unroll
        for (int p = 0; p < 4; ++p)
          acc[q][p] = __builtin_amdgcn_mfma_f32_16x16x32_fp8_fp8(bfr[p][kh], af[kh], acc[q][p], 0, 0, 0);
    }
    __builtin_amdgcn_s_setprio(0);

    __builtin_amdgcn_sched_barrier(0);
    __builtin_amdgcn_s_barrier();
    __builtin_amdgcn_sched_barrier(0);
    stageA(g + 2, buf);
    stageB(g + 2, buf);
  }

  const int colq = (lane >> 4) * 4;
  float4 bias4[4];
#pragma unroll
  for (int p = 0; p < 4; ++p) {
    int colbase = n0 + wn * 64 + p * 16 + colq;
    bias4[p] = (colbase < Nd) ? *(const float4*)(bias + colbase) : make_float4(0.f, 0.f, 0.f, 0.f);
  }
#pragma unroll
  for (int q = 0; q < 8; ++q) {
    int row = m0 + wm * 128 + q * 16 + (lane & 15);
#pragma unroll
    for (int p = 0; p < 4; ++p) {
      int colbase = n0 + wn * 64 + p * 16 + colq;
      if (colbase < Nd) {
        f32x4 v = acc[q][p];
        float4 o = make_float4(v[0] + bias4[p].x, v[1] + bias4[p].y,
                               v[2] + bias4[p].z, v[3] + bias4[p].w);
        *(float4*)(&C[(size_t)row * ldc + colbase]) = o;
      }
    }
  }
}

// ================= fused launches =================

// launch 1: trW1(128) | trW2(64) | trW3(96) | cmag(1000) | mag(2048)  = 3336 blocks
__global__ __launch_bounds__(256) void k_pre(const float* W1, __hip_bfloat16* w1t,
                                             const float* W2, __hip_bfloat16* w2t,
                                             const float* W3, __hip_bfloat16* w3t,
                                             const float* cre, const float* cim, float* cmagT, float* yn,
                                             const float* sre, const float* simg, float* mag,
                                             __hip_bfloat16* xcat, float* xn) {
  __shared__ float t32[64][65];
  __shared__ double red[4];
  int bid = blockIdx.x;
  if (bid < 128) {
    dev_tr<0>(t32, W1, (void*)w1t, 1024, 512, bid & 7, bid >> 3);
  } else if (bid < 192) {
    int t = bid - 128;
    dev_tr<0>(t32, W2, (void*)w2t, 512, 512, t & 7, t >> 3);
  } else if (bid < 288) {
    int t = bid - 192;
    dev_tr<0>(t32, W3, (void*)w3t, 512, 768, t % 12, t / 12);
  } else if (bid < 1288) {
    dev_cmag(red, cre, cim, cmagT, yn, bid - 288);
  } else {
    dev_mag(red, sre, simg, mag, xcat, xn, bid - 1288);
  }
}

// launch 2: MLP-L1 (64 blocks, grid 4x16) | trW4 fp8 (9408 blocks, grid 784x12)
__global__ __launch_bounds__(256) void k_l1w4(const __hip_bfloat16* xcat, const __hip_bfloat16* w1t,
                                              __hip_bfloat16* h1b, const float* b1,
                                              const float* W4, unsigned char* w4f8) {
  __shared__ short Al[128 * 32];
  __shared__ short Bl[128 * 32];
  __shared__ float t32[64][65];
  int bid = blockIdx.x;
  if (bid < 64) {
    dev_mlp<0>(Al, Bl, xcat, w1t, (void*)h1b, 2048, 512, 1024, 512, b1, bid & 3, bid >> 2);
  } else {
    int t = bid - 64;
    dev_tr<1>(t32, W4, (void*)w4f8, 768, 50000, t % 784, t / 784);
  }
}

// launch 3/4: MLP L2 (bf16 out) / L3 (fp8 out), standalone
template <int OUTT>
__global__ __launch_bounds__(256) void k_mlp(const __hip_bfloat16* A, const __hip_bfloat16* Bt,
                                             void* C, int M, int N, int K, int ldc, const float* bias) {
  __shared__ short Al[128 * 32];
  __shared__ short Bl[128 * 32];
  dev_mlp<OUTT>(Al, Bl, A, Bt, C, M, N, K, ldc, bias, blockIdx.x, blockIdx.y);
}

// launch 5: gemm_v9 (3136) + dots (512) fused. 456 groups of 8; groups g%7==3 (g<=444) are dots
// (64 groups x 8 = 512); physical bid&7 -> XCD cohort mapping of gemm tiles preserved exactly.
// LDS union 48KB -> CU fits 2 gemm + 1 dots (144KB). dots = f64 VALU, gemm = MFMA: m114 overlap.
union KMainSmem {
  struct { unsigned char As[2][16384]; unsigned char Bs[2][8192]; } g;
  struct { double As[16][64]; double Bs[16][64]; } d;
};

__global__ __launch_bounds__(256, 2) void k_main(const unsigned char* __restrict__ A8,
                                                 const unsigned char* __restrict__ B8,
                                                 float* __restrict__ C, const float* __restrict__ bias,
                                                 const float* __restrict__ mag,
                                                 const float* __restrict__ cmagT,
                                                 float* __restrict__ simsb,
                                                 const float* __restrict__ xn,
                                                 const float* __restrict__ yn) {
  __shared__ KMainSmem sm;
  const int bid = blockIdx.x;
  const int g = bid >> 3;
  const bool isDots = ((g % 7) == 3) && (g <= 444);
  if (isDots) {
    int dgi = (g - 3) / 7;                 // 0..63
    int id = dgi * 8 + (bid & 7);          // 0..511
    dev_dots(sm.d.As, sm.d.Bs, mag, cmagT, simsb, 2048, 1000, 512, 1000, xn, yn,
             id & 15, id >> 4);            // nb, mb
  } else {
    int dots_before = (g < 3) ? 0 : min(64, (g + 4) / 7);
    int jg = g - dots_before;              // 0..391
    dev_gemm(sm.g.As, sm.g.Bs, A8, B8, C, bias, bid & 7, jg);
  }
}

// launch 6: top-5 per row (one wave per row)
__global__ __launch_bounds__(256) void k_topk(const float* __restrict__ sims,
                                              float* __restrict__ top_sims, float* __restrict__ top_idx) {
  int lane = threadIdx.x & 63, wave = threadIdx.x >> 6;
  int row = blockIdx.x * 4 + wave;
  const float* s = sims + (size_t)row * 1000;
  float v[16];
  int idx[16];
#pragma unroll
  for (int t = 0; t < 16; ++t) {
    int c = lane + t * 64;
    if (c < 1000) { v[t] = s[c]; idx[t] = c; }
    else { v[t] = -1e30f; idx[t] = 1 << 20; }
  }
  for (int j = 0; j < 5; ++j) {
    float bv = -1e30f; int bi = 1 << 20;
#pragma unroll
    for (int t = 0; t < 16; ++t) {
      if (v[t] > bv || (v[t] == bv && idx[t] < bi)) { bv = v[t]; bi = idx[t]; }
    }
    float rv = bv; int ri = bi;
#pragma unroll
    for (int off = 32; off; off >>= 1) {
      float ov = __shfl_xor(rv, off);
      int oi = __shfl_xor(ri, off);
      if (ov > rv || (ov == rv && oi < ri)) { rv = ov; ri = oi; }
    }
    if (lane == 0) {
      top_sims[(size_t)row * 5 + j] = rv;
      top_idx[(size_t)row * 5 + j] = (float)ri;
    }
#pragma unroll
    for (int t = 0; t < 16; ++t)
      if (idx[t] == ri) v[t] = -1e30f;
  }
}

extern "C" void kernel_launch(void* const* d_in, const int* in_sizes, int n_in,
                              void* d_out, int out_size, void* d_ws, size_t ws_size,
                              hipStream_t stream) {
  const float* sre = (const float*)d_in[0];
  const float* simg = (const float*)d_in[1];
  const float* cre = (const float*)d_in[2];
  const float* cim = (const float*)d_in[3];
  const float* W1 = (const float*)d_in[4];
  const float* b1 = (const float*)d_in[5];
  const float* W2 = (const float*)d_in[6];
  const float* b2 = (const float*)d_in[7];
  const float* W3 = (const float*)d_in[8];
  const float* b3 = (const float*)d_in[9];
  const float* W4 = (const float*)d_in[10];
  const float* b4 = (const float*)d_in[11];

  const int M = 2048, D = 512, Cc = 1000, V = 50000, K1 = 1024, H3 = 768;
  const int Npad2 = 392 * 128;  // 50176

  char* ws = (char*)d_ws;
  size_t off = 0;
  auto alloc = [&](size_t bytes) {
    char* p = ws + off;
    off = (off + bytes + 255) & ~(size_t)255;
    return p;
  };
  __hip_bfloat16* xcatb = (__hip_bfloat16*)alloc((size_t)M * K1 * 2);
  float* mag = (float*)alloc((size_t)M * D * 4);
  float* cmagT = (float*)alloc((size_t)D * Cc * 4);
  float* xn = (float*)alloc((size_t)M * 4);
  float* yn = (float*)alloc((size_t)Cc * 4);
  float* simsb = (float*)alloc((size_t)M * Cc * 4);
  __hip_bfloat16* h1b = (__hip_bfloat16*)alloc((size_t)M * 512 * 2);
  __hip_bfloat16* h2b = (__hip_bfloat16*)alloc((size_t)M * 512 * 2);
  unsigned char* h3f8 = (unsigned char*)alloc((size_t)M * H3);
  __hip_bfloat16* w1t = (__hip_bfloat16*)alloc((size_t)512 * K1 * 2);
  __hip_bfloat16* w2t = (__hip_bfloat16*)alloc((size_t)512 * 512 * 2);
  __hip_bfloat16* w3t = (__hip_bfloat16*)alloc((size_t)H3 * 512 * 2);
  unsigned char* w4f8 = (unsigned char*)alloc((size_t)Npad2 * H3);

  float* top_sims = (float*)d_out;
  float* top_idx = (float*)d_out + (size_t)M * 5;
  float* logits = (float*)d_out + (size_t)M * 5 * 2;

  // 1: weight transposes W1-3 + cmag + mag (all independent)
  k_pre<<<dim3(3336), dim3(256), 0, stream>>>(W1, w1t, W2, w2t, W3, w3t,
                                              cre, cim, cmagT, yn, sre, simg, mag, xcatb, xn);
  // 2: MLP-L1 overlapped with W4 transpose
  k_l1w4<<<dim3(64 + 9408), dim3(256), 0, stream>>>(xcatb, w1t, h1b, b1, W4, w4f8);
  // 3,4: MLP L2, L3
  k_mlp<0><<<dim3(4, 16), dim3(256), 0, stream>>>(h1b, w2t, (void*)h2b, M, 512, 512, 512, b2);
  k_mlp<1><<<dim3(6, 16), dim3(256), 0, stream>>>(h2b, w3t, (void*)h3f8, M, H3, 512, H3, b3);
  // 5: big GEMM + dots fused (m114 MFMA/VALU overlap)
  k_main<<<dim3(3648), dim3(256), 0, stream>>>(h3f8, w4f8, logits, b4, mag, cmagT, simsb, xn, yn);
  // 6: top-k
  k_topk<<<dim3(M / 4), dim3(256), 0, stream>>>(simsb, top_sims, top_idx);
}

// Round 11
// 390.164 us; speedup vs baseline: 1.2967x; 1.0436x over previous
//
#include <hip/hip_runtime.h>
#include <hip/hip_bf16.h>
#include <hip/hip_fp8.h>

#define CEPS 1e-8f

typedef __attribute__((ext_vector_type(8))) __bf16 bf16x8;
typedef __attribute__((ext_vector_type(4))) float f32x4;

__device__ __forceinline__ void gload_lds16(const void* g, void* l) {
  __builtin_amdgcn_global_load_lds((const __attribute__((address_space(1))) unsigned int*)g,
                                   (__attribute__((address_space(3))) unsigned int*)l, 16, 0, 0);
}

__device__ __forceinline__ float gelu_f(float v) {
  return 0.5f * v * (1.0f + erff(v * 0.70710678118654752f));
}

__device__ __forceinline__ unsigned char f32_to_e4m3(float v) {
  __hip_fp8_e4m3 t(v);
  return (unsigned char)t.__x;
}

// ================= device bodies =================

// ---- magnitude + concat(bf16) + row norm ----
__device__ __forceinline__ void dev_mag(double* red, const float* __restrict__ re,
                                        const float* __restrict__ im, float* __restrict__ mag,
                                        __hip_bfloat16* __restrict__ xcat, float* __restrict__ xn,
                                        int row) {
  const float* r = re + (size_t)row * 512;
  const float* q = im + (size_t)row * 512;
  double ss = 0.0;
  for (int d = threadIdx.x; d < 512; d += 256) {
    float a = r[d], b = q[d];
    float s = __fadd_rn(__fmul_rn(a, a), __fmul_rn(b, b));  // match np rounding
    float m = __fsqrt_rn(s);
    mag[(size_t)row * 512 + d] = m;
    xcat[(size_t)row * 1024 + d] = __float2bfloat16(a);
    xcat[(size_t)row * 1024 + 512 + d] = __float2bfloat16(b);
    ss += (double)m * (double)m;
  }
  for (int off = 32; off; off >>= 1) ss += __shfl_xor(ss, off);
  int lane = threadIdx.x & 63, wave = threadIdx.x >> 6;
  if (lane == 0) red[wave] = ss;
  __syncthreads();
  if (threadIdx.x == 0) {
    double tot = red[0] + red[1] + red[2] + red[3];
    float n = (float)sqrt(tot);
    xn[row] = fmaxf(n, CEPS);
  }
}

// ---- concept magnitude (transposed) + norms ----
__device__ __forceinline__ void dev_cmag(double* red, const float* __restrict__ cre,
                                         const float* __restrict__ cim, float* __restrict__ cmagT,
                                         float* __restrict__ yn, int c) {
  const float* r = cre + (size_t)c * 512;
  const float* q = cim + (size_t)c * 512;
  double ss = 0.0;
  for (int d = threadIdx.x; d < 512; d += 256) {
    float a = r[d], b = q[d];
    float s = __fadd_rn(__fmul_rn(a, a), __fmul_rn(b, b));
    float m = __fsqrt_rn(s);
    cmagT[(size_t)d * 1000 + c] = m;
    ss += (double)m * (double)m;
  }
  for (int off = 32; off; off >>= 1) ss += __shfl_xor(ss, off);
  int lane = threadIdx.x & 63, wave = threadIdx.x >> 6;
  if (lane == 0) red[wave] = ss;
  __syncthreads();
  if (threadIdx.x == 0) {
    double tot = red[0] + red[1] + red[2] + red[3];
    float n = (float)sqrt(tot);
    yn[c] = fmaxf(n, CEPS);
  }
}

// ---- transpose: W[K,N] f32 -> Wt[n][k] (OUTT 0=bf16, 1=fp8; zero-pad n>=N) ----
template <int OUTT>
__device__ __forceinline__ void dev_tr(float (*t32)[65], const float* __restrict__ W,
                                       void* __restrict__ Wt, int K, int N, int bx, int by) {
  int n0 = bx * 64, k0 = by * 64;
  int tid = threadIdx.x;
  {
    int nc = tid & 15, kr4 = tid >> 4;
#pragma unroll
    for (int p = 0; p < 4; ++p) {
      int kr = p * 16 + kr4;
      int n = n0 + nc * 4;
      float4 v = make_float4(0.f, 0.f, 0.f, 0.f);
      if (n < N) v = *(const float4*)(W + (size_t)(k0 + kr) * N + n);
      t32[kr][nc * 4 + 0] = v.x; t32[kr][nc * 4 + 1] = v.y;
      t32[kr][nc * 4 + 2] = v.z; t32[kr][nc * 4 + 3] = v.w;
    }
  }
  __syncthreads();
  {
    int kc = tid & 15, nr4 = tid >> 4;
#pragma unroll
    for (int p = 0; p < 4; ++p) {
      int nr = p * 16 + nr4;
      if (OUTT == 0) {
        ushort4 o;
        __hip_bfloat16 h0 = __float2bfloat16(t32[kc * 4 + 0][nr]);
        __hip_bfloat16 h1 = __float2bfloat16(t32[kc * 4 + 1][nr]);
        __hip_bfloat16 h2 = __float2bfloat16(t32[kc * 4 + 2][nr]);
        __hip_bfloat16 h3 = __float2bfloat16(t32[kc * 4 + 3][nr]);
        o.x = *(unsigned short*)&h0; o.y = *(unsigned short*)&h1;
        o.z = *(unsigned short*)&h2; o.w = *(unsigned short*)&h3;
        *(ushort4*)((unsigned short*)Wt + (size_t)(n0 + nr) * K + k0 + kc * 4) = o;
      } else {
        unsigned int o = (unsigned int)f32_to_e4m3(t32[kc * 4 + 0][nr]) |
                         ((unsigned int)f32_to_e4m3(t32[kc * 4 + 1][nr]) << 8) |
                         ((unsigned int)f32_to_e4m3(t32[kc * 4 + 2][nr]) << 16) |
                         ((unsigned int)f32_to_e4m3(t32[kc * 4 + 3][nr]) << 24);
        *(unsigned int*)((unsigned char*)Wt + (size_t)(n0 + nr) * K + k0 + kc * 4) = o;
      }
    }
  }
}

// ---- 128x128 bf16 MFMA GEMM with gelu epilogue (MLP layers) ----
template <int OUTT>
__device__ __forceinline__ void dev_mlp(short* Al, short* Bl, const __hip_bfloat16* __restrict__ A,
                                        const __hip_bfloat16* __restrict__ Bt, void* __restrict__ C,
                                        int M, int N, int K, int ldc, const float* __restrict__ bias,
                                        int bx, int by) {
  const int tid = threadIdx.x, lane = tid & 63, wave = tid >> 6;
  const int m0 = by * 128, n0 = bx * 128;
  const int wr = wave >> 1, wc = wave & 1;
  f32x4 acc[4][4];
  f32x4 zero4 = {0.f, 0.f, 0.f, 0.f};
#pragma unroll
  for (int i = 0; i < 4; ++i)
#pragma unroll
    for (int j = 0; j < 4; ++j) acc[i][j] = zero4;

  const short* Ag = (const short*)A;
  const short* Bg = (const short*)Bt;
  for (int k0 = 0; k0 < K; k0 += 32) {
#pragma unroll
    for (int s = 0; s < 2; ++s) {
      int seg = wave + s * 4;
      int elem = seg * 512 + lane * 8;
      int row = elem >> 5, kk = elem & 31;
      gload_lds16(Ag + (size_t)(m0 + row) * K + k0 + kk, Al + elem);
      gload_lds16(Bg + (size_t)(n0 + row) * K + k0 + kk, Bl + elem);
    }
    __syncthreads();
    bf16x8 af[4], bfr[4];
    const int fr = lane & 15, fk = (lane >> 4) << 3;
#pragma unroll
    for (int i = 0; i < 4; ++i)
      af[i] = *(const bf16x8*)(Al + (wr * 64 + i * 16 + fr) * 32 + fk);
#pragma unroll
    for (int j = 0; j < 4; ++j)
      bfr[j] = *(const bf16x8*)(Bl + (wc * 64 + j * 16 + fr) * 32 + fk);
#pragma unroll
    for (int i = 0; i < 4; ++i)
#pragma unroll
      for (int j = 0; j < 4; ++j)
        acc[i][j] = __builtin_amdgcn_mfma_f32_16x16x32_bf16(af[i], bfr[j], acc[i][j], 0, 0, 0);
    __syncthreads();
  }
  const int fr = lane & 15, fq = lane >> 4;
#pragma unroll
  for (int j = 0; j < 4; ++j) {
    int col = n0 + wc * 64 + j * 16 + fr;
    if (col >= N) continue;
    float bv = bias[col];
#pragma unroll
    for (int i = 0; i < 4; ++i) {
      int rbase = m0 + wr * 64 + i * 16 + fq * 4;
#pragma unroll
      for (int r = 0; r < 4; ++r) {
        float v = gelu_f(acc[i][j][r] + bv);
        if (OUTT == 0)
          ((__hip_bfloat16*)C)[(size_t)(rbase + r) * ldc + col] = __float2bfloat16(v);
        else
          ((unsigned char*)C)[(size_t)(rbase + r) * ldc + col] = f32_to_e4m3(v);
      }
    }
  }
}

// ---- dots GEMM, f64 acc; LDS padded [16][65] -> write patterns conflict-free.
// FMA order identical to rounds 7-10 (bitwise-same sims -> top-k safe).
__device__ __forceinline__ void dev_dots(double (*As)[65], double (*Bs)[65],
                                         const float* __restrict__ A, const float* __restrict__ Bm,
                                         float* __restrict__ Cm, int M, int N, int K, int ldc,
                                         const float* __restrict__ xn, const float* __restrict__ yn,
                                         int nb, int mb) {
  const int tid = threadIdx.x;
  const int m0 = mb * 64, n0 = nb * 64;
  const int tx = tid & 15, ty4 = tid >> 4;
  const int ar = tid >> 2, ak = (tid & 3) << 2;
  const int bk = tid >> 4, bn = (tid & 15) << 2;
  double acc[4][4] = {};
  for (int k0 = 0; k0 < K; k0 += 16) {
    float4 a4 = *(const float4*)(A + (size_t)(m0 + ar) * K + k0 + ak);
    As[ak + 0][ar] = (double)a4.x; As[ak + 1][ar] = (double)a4.y;
    As[ak + 2][ar] = (double)a4.z; As[ak + 3][ar] = (double)a4.w;
    float4 b4 = make_float4(0.f, 0.f, 0.f, 0.f);
    if (n0 + bn < N) b4 = *(const float4*)(Bm + (size_t)(k0 + bk) * N + n0 + bn);
    Bs[bk][bn + 0] = (double)b4.x; Bs[bk][bn + 1] = (double)b4.y;
    Bs[bk][bn + 2] = (double)b4.z; Bs[bk][bn + 3] = (double)b4.w;
    __syncthreads();
#pragma unroll
    for (int kk = 0; kk < 16; ++kk) {
      double av[4], bv[4];
#pragma unroll
      for (int i = 0; i < 4; ++i) av[i] = As[kk][ty4 + i * 16];
#pragma unroll
      for (int j = 0; j < 4; ++j) bv[j] = Bs[kk][tx + j * 16];
#pragma unroll
      for (int i = 0; i < 4; ++i)
#pragma unroll
        for (int j = 0; j < 4; ++j)
          acc[i][j] = fma(av[i], bv[j], acc[i][j]);
    }
    __syncthreads();
  }
#pragma unroll
  for (int i = 0; i < 4; ++i) {
    int row = m0 + ty4 + i * 16;
#pragma unroll
    for (int j = 0; j < 4; ++j) {
      int col = n0 + tx + j * 16;
      if (col >= N) continue;
      double d = acc[i][j] / ((double)xn[row] * (double)yn[col]);
      Cm[(size_t)row * ldc + col] = (float)d;
    }
  }
}

// ---- top-5 per row (one wave per row; 4 rows per block) ----
__device__ __forceinline__ void dev_topk(const float* __restrict__ sims,
                                         float* __restrict__ top_sims, float* __restrict__ top_idx,
                                         int rowblock) {
  int lane = threadIdx.x & 63, wave = threadIdx.x >> 6;
  int row = rowblock * 4 + wave;
  const float* s = sims + (size_t)row * 1000;
  float v[16];
  int idx[16];
#pragma unroll
  for (int t = 0; t < 16; ++t) {
    int c = lane + t * 64;
    if (c < 1000) { v[t] = s[c]; idx[t] = c; }
    else { v[t] = -1e30f; idx[t] = 1 << 20; }
  }
  for (int j = 0; j < 5; ++j) {
    float bv = -1e30f; int bi = 1 << 20;
#pragma unroll
    for (int t = 0; t < 16; ++t) {
      if (v[t] > bv || (v[t] == bv && idx[t] < bi)) { bv = v[t]; bi = idx[t]; }
    }
    float rv = bv; int ri = bi;
#pragma unroll
    for (int off = 32; off; off >>= 1) {
      float ov = __shfl_xor(rv, off);
      int oi = __shfl_xor(ri, off);
      if (ov > rv || (ov == rv && oi < ri)) { rv = ov; ri = oi; }
    }
    if (lane == 0) {
      top_sims[(size_t)row * 5 + j] = rv;
      top_idx[(size_t)row * 5 + j] = (float)ri;
    }
#pragma unroll
    for (int t = 0; t < 16; ++t)
      if (idx[t] == ri) v[t] = -1e30f;
  }
}

// ---- final-layer fp8 GEMM body (round-9 gemm_v9 + setprio) ----
__device__ __forceinline__ void dev_gemm(unsigned char (*As)[16384], unsigned char (*Bs)[8192],
                                         const unsigned char* __restrict__ A8,
                                         const unsigned char* __restrict__ B8,
                                         float* __restrict__ C, const float* __restrict__ bias,
                                         int xcd, int j) {
  const int KNT = 12;
  const int Kd = 768, Nd = 50000, ldc = 50000;
  const int tid = threadIdx.x, lane = tid & 63, wave = tid >> 6;
  const int wm = wave >> 1, wn = wave & 1;

  const int mt = j & 7;
  const int ntile = xcd + 8 * (j >> 3);
  const int m0 = mt * 256, n0 = ntile * 128;

  f32x4 acc[8][4];
  f32x4 z4 = {0.f, 0.f, 0.f, 0.f};
#pragma unroll
  for (int q = 0; q < 8; ++q)
#pragma unroll
    for (int p = 0; p < 4; ++p) acc[q][p] = z4;

  auto stageA = [&](int kt, int buf) {
    if (kt >= KNT) return;
    const int k0 = kt * 64;
#pragma unroll
    for (int r = 0; r < 4; ++r) {
      int idx = r * 256 + tid;
      int row = idx >> 2, c = idx & 3;
      int src = ((c * 2) ^ (row & 6)) * 8;
      gload_lds16(A8 + (size_t)(m0 + row) * Kd + k0 + src, &As[buf][row * 64 + c * 16]);
    }
  };
  auto stageB = [&](int kt, int buf) {
    if (kt >= KNT) return;
    const int k0 = kt * 64;
#pragma unroll
    for (int r = 0; r < 2; ++r) {
      int idx = r * 256 + tid;
      int row = idx >> 2, c = idx & 3;
      int src = ((c * 2) ^ (row & 6)) * 8;
      gload_lds16(B8 + (size_t)(n0 + row) * Kd + k0 + src, &Bs[buf][row * 64 + c * 16]);
    }
  };

  stageA(0, 0); stageB(0, 0);
  stageA(1, 1); stageB(1, 1);

  for (int g = 0; g < KNT; ++g) {
    const int buf = g & 1;
    if (g < KNT - 1) asm volatile("s_waitcnt vmcnt(6)" ::: "memory");
    else             asm volatile("s_waitcnt vmcnt(0)" ::: "memory");
    __builtin_amdgcn_sched_barrier(0);
    __builtin_amdgcn_s_barrier();
    __builtin_amdgcn_sched_barrier(0);

    long bfr[4][2];
#pragma unroll
    for (int p = 0; p < 4; ++p) {
      int row = wn * 64 + p * 16 + (lane & 15);
#pragma unroll
      for (int kh = 0; kh < 2; ++kh) {
        int slot = (kh * 4 + (lane >> 4)) ^ (row & 6);
        bfr[p][kh] = *(const long*)(&Bs[buf][row * 64 + slot * 8]);
      }
    }
    __builtin_amdgcn_s_setprio(1);
#pragma unroll
    for (int q = 0; q < 8; ++q) {
      int rowA = wm * 128 + q * 16 + (lane & 15);
      long af[2];
#pragma unroll
      for (int kh = 0; kh < 2; ++kh) {
        int slot = (kh * 4 + (lane >> 4)) ^ (rowA & 6);
        af[kh] = *(const long*)(&As[buf][rowA * 64 + slot * 8]);
      }
#pragma unroll
      for (int kh = 0; kh < 2; ++kh)
#pragma unroll
        for (int p = 0; p < 4; ++p)
          acc[q][p] = __builtin_amdgcn_mfma_f32_16x16x32_fp8_fp8(bfr[p][kh], af[kh], acc[q][p], 0, 0, 0);
    }
    __builtin_amdgcn_s_setprio(0);

    __builtin_amdgcn_sched_barrier(0);
    __builtin_amdgcn_s_barrier();
    __builtin_amdgcn_sched_barrier(0);
    stageA(g + 2, buf);
    stageB(g + 2, buf);
  }

  const int colq = (lane >> 4) * 4;
  float4 bias4[4];
#pragma unroll
  for (int p = 0; p < 4; ++p) {
    int colbase = n0 + wn * 64 + p * 16 + colq;
    bias4[p] = (colbase < Nd) ? *(const float4*)(bias + colbase) : make_float4(0.f, 0.f, 0.f, 0.f);
  }
#pragma unroll
  for (int q = 0; q < 8; ++q) {
    int row = m0 + wm * 128 + q * 16 + (lane & 15);
#pragma unroll
    for (int p = 0; p < 4; ++p) {
      int colbase = n0 + wn * 64 + p * 16 + colq;
      if (colbase < Nd) {
        f32x4 v = acc[q][p];
        float4 o = make_float4(v[0] + bias4[p].x, v[1] + bias4[p].y,
                               v[2] + bias4[p].z, v[3] + bias4[p].w);
        *(float4*)(&C[(size_t)row * ldc + colbase]) = o;
      }
    }
  }
}

// ================= fused launches =================

// launch 1: trW1(128) | trW2(64) | trW3(96) | cmag(1000) | mag(2048)  = 3336 blocks
__global__ __launch_bounds__(256) void k_pre(const float* W1, __hip_bfloat16* w1t,
                                             const float* W2, __hip_bfloat16* w2t,
                                             const float* W3, __hip_bfloat16* w3t,
                                             const float* cre, const float* cim, float* cmagT, float* yn,
                                             const float* sre, const float* simg, float* mag,
                                             __hip_bfloat16* xcat, float* xn) {
  __shared__ float t32[64][65];
  __shared__ double red[4];
  int bid = blockIdx.x;
  if (bid < 128) {
    dev_tr<0>(t32, W1, (void*)w1t, 1024, 512, bid & 7, bid >> 3);
  } else if (bid < 192) {
    int t = bid - 128;
    dev_tr<0>(t32, W2, (void*)w2t, 512, 512, t & 7, t >> 3);
  } else if (bid < 288) {
    int t = bid - 192;
    dev_tr<0>(t32, W3, (void*)w3t, 512, 768, t % 12, t / 12);
  } else if (bid < 1288) {
    dev_cmag(red, cre, cim, cmagT, yn, bid - 288);
  } else {
    dev_mag(red, sre, simg, mag, xcat, xn, bid - 1288);
  }
}

// launch 2: MLP-L1 (64) | dots (512, HBM-light VALU work hides under transpose) | trW4 fp8 (9408)
union L1W4Smem {
  struct { short Al[128 * 32]; short Bl[128 * 32]; } m;
  float t32[64][65];
  struct { double As[16][65]; double Bs[16][65]; } d;
};
__global__ __launch_bounds__(256) void k_l1w4(const __hip_bfloat16* xcat, const __hip_bfloat16* w1t,
                                              __hip_bfloat16* h1b, const float* b1,
                                              const float* W4, unsigned char* w4f8,
                                              const float* mag, const float* cmagT, float* simsb,
                                              const float* xn, const float* yn) {
  __shared__ L1W4Smem sm;
  int bid = blockIdx.x;
  if (bid < 64) {
    dev_mlp<0>(sm.m.Al, sm.m.Bl, xcat, w1t, (void*)h1b, 2048, 512, 1024, 512, b1, bid & 3, bid >> 2);
  } else if (bid < 576) {
    int id = bid - 64;  // 0..511
    dev_dots(sm.d.As, sm.d.Bs, mag, cmagT, simsb, 2048, 1000, 512, 1000, xn, yn,
             id & 15, id >> 4);
  } else {
    int t = bid - 576;
    dev_tr<1>(sm.t32, W4, (void*)w4f8, 768, 50000, t % 784, t / 784);
  }
}

// launch 3: MLP-L2 (64, bf16 out) | topk (512)
__global__ __launch_bounds__(256) void k_l2topk(const __hip_bfloat16* h1b, const __hip_bfloat16* w2t,
                                                __hip_bfloat16* h2b, const float* b2,
                                                const float* simsb, float* top_sims, float* top_idx) {
  __shared__ short Al[128 * 32];
  __shared__ short Bl[128 * 32];
  int bid = blockIdx.x;
  if (bid < 64) {
    dev_mlp<0>(Al, Bl, h1b, w2t, (void*)h2b, 2048, 512, 512, 512, b2, bid & 3, bid >> 2);
  } else {
    dev_topk(simsb, top_sims, top_idx, bid - 64);
  }
}

// launch 4: MLP-L3 (fp8 out)
__global__ __launch_bounds__(256) void k_l3(const __hip_bfloat16* h2b, const __hip_bfloat16* w3t,
                                            unsigned char* h3f8, const float* b3) {
  __shared__ short Al[128 * 32];
  __shared__ short Bl[128 * 32];
  dev_mlp<1>(Al, Bl, h2b, w3t, (void*)h3f8, 2048, 768, 512, 768, b3, blockIdx.x % 6, blockIdx.x / 6);
}

// launch 5: pure fp8 GEMM (3136 blocks, r9 structure)
__global__ __launch_bounds__(256, 2) void k_main(const unsigned char* __restrict__ A8,
                                                 const unsigned char* __restrict__ B8,
                                                 float* __restrict__ C, const float* __restrict__ bias) {
  __shared__ unsigned char As[2][16384];
  __shared__ unsigned char Bs[2][8192];
  dev_gemm(As, Bs, A8, B8, C, bias, blockIdx.x & 7, blockIdx.x >> 3);
}

extern "C" void kernel_launch(void* const* d_in, const int* in_sizes, int n_in,
                              void* d_out, int out_size, void* d_ws, size_t ws_size,
                              hipStream_t stream) {
  const float* sre = (const float*)d_in[0];
  const float* simg = (const float*)d_in[1];
  const float* cre = (const float*)d_in[2];
  const float* cim = (const float*)d_in[3];
  const float* W1 = (const float*)d_in[4];
  const float* b1 = (const float*)d_in[5];
  const float* W2 = (const float*)d_in[6];
  const float* b2 = (const float*)d_in[7];
  const float* W3 = (const float*)d_in[8];
  const float* b3 = (const float*)d_in[9];
  const float* W4 = (const float*)d_in[10];
  const float* b4 = (const float*)d_in[11];

  const int M = 2048, D = 512, Cc = 1000, V = 50000, K1 = 1024, H3 = 768;
  const int Npad2 = 392 * 128;  // 50176

  char* ws = (char*)d_ws;
  size_t off = 0;
  auto alloc = [&](size_t bytes) {
    char* p = ws + off;
    off = (off + bytes + 255) & ~(size_t)255;
    return p;
  };
  __hip_bfloat16* xcatb = (__hip_bfloat16*)alloc((size_t)M * K1 * 2);
  float* mag = (float*)alloc((size_t)M * D * 4);
  float* cmagT = (float*)alloc((size_t)D * Cc * 4);
  float* xn = (float*)alloc((size_t)M * 4);
  float* yn = (float*)alloc((size_t)Cc * 4);
  float* simsb = (float*)alloc((size_t)M * Cc * 4);
  __hip_bfloat16* h1b = (__hip_bfloat16*)alloc((size_t)M * 512 * 2);
  __hip_bfloat16* h2b = (__hip_bfloat16*)alloc((size_t)M * 512 * 2);
  unsigned char* h3f8 = (unsigned char*)alloc((size_t)M * H3);
  __hip_bfloat16* w1t = (__hip_bfloat16*)alloc((size_t)512 * K1 * 2);
  __hip_bfloat16* w2t = (__hip_bfloat16*)alloc((size_t)512 * 512 * 2);
  __hip_bfloat16* w3t = (__hip_bfloat16*)alloc((size_t)H3 * 512 * 2);
  unsigned char* w4f8 = (unsigned char*)alloc((size_t)Npad2 * H3);

  float* top_sims = (float*)d_out;
  float* top_idx = (float*)d_out + (size_t)M * 5;
  float* logits = (float*)d_out + (size_t)M * 5 * 2;

  // 1: weight transposes W1-3 + cmag + mag (all independent)
  k_pre<<<dim3(3336), dim3(256), 0, stream>>>(W1, w1t, W2, w2t, W3, w3t,
                                              cre, cim, cmagT, yn, sre, simg, mag, xcatb, xn);
  // 2: MLP-L1 + dots + W4 transpose (dots VALU hides under transpose HBM)
  k_l1w4<<<dim3(64 + 512 + 9408), dim3(256), 0, stream>>>(xcatb, w1t, h1b, b1, W4, w4f8,
                                                          mag, cmagT, simsb, xn, yn);
  // 3: MLP-L2 + top-k
  k_l2topk<<<dim3(64 + 512), dim3(256), 0, stream>>>(h1b, w2t, h2b, b2, simsb, top_sims, top_idx);
  // 4: MLP-L3
  k_l3<<<dim3(96), dim3(256), 0, stream>>>(h2b, w3t, h3f8, b3);
  // 5: big fp8 GEMM (pure)
  k_main<<<dim3(3136), dim3(256), 0, stream>>>(h3f8, w4f8, logits, b4);
}

// Round 12
// 389.639 us; speedup vs baseline: 1.2984x; 1.0013x over previous
//
#include <hip/hip_runtime.h>
#include <hip/hip_bf16.h>
#include <hip/hip_fp8.h>

#define CEPS 1e-8f

typedef __attribute__((ext_vector_type(8))) __bf16 bf16x8;
typedef __attribute__((ext_vector_type(4))) float f32x4;

__device__ __forceinline__ void gload_lds16(const void* g, void* l) {
  __builtin_amdgcn_global_load_lds((const __attribute__((address_space(1))) unsigned int*)g,
                                   (__attribute__((address_space(3))) unsigned int*)l, 16, 0, 0);
}

__device__ __forceinline__ float gelu_f(float v) {
  return 0.5f * v * (1.0f + erff(v * 0.70710678118654752f));
}

__device__ __forceinline__ unsigned char f32_to_e4m3(float v) {
  __hip_fp8_e4m3 t(v);
  return (unsigned char)t.__x;
}

// ================= device bodies =================

// ---- magnitude + concat(bf16) + row norm ----
__device__ __forceinline__ void dev_mag(double* red, const float* __restrict__ re,
                                        const float* __restrict__ im, float* __restrict__ mag,
                                        __hip_bfloat16* __restrict__ xcat, float* __restrict__ xn,
                                        int row) {
  const float* r = re + (size_t)row * 512;
  const float* q = im + (size_t)row * 512;
  double ss = 0.0;
  for (int d = threadIdx.x; d < 512; d += 256) {
    float a = r[d], b = q[d];
    float s = __fadd_rn(__fmul_rn(a, a), __fmul_rn(b, b));  // match np rounding
    float m = __fsqrt_rn(s);
    mag[(size_t)row * 512 + d] = m;
    xcat[(size_t)row * 1024 + d] = __float2bfloat16(a);
    xcat[(size_t)row * 1024 + 512 + d] = __float2bfloat16(b);
    ss += (double)m * (double)m;
  }
  for (int off = 32; off; off >>= 1) ss += __shfl_xor(ss, off);
  int lane = threadIdx.x & 63, wave = threadIdx.x >> 6;
  if (lane == 0) red[wave] = ss;
  __syncthreads();
  if (threadIdx.x == 0) {
    double tot = red[0] + red[1] + red[2] + red[3];
    float n = (float)sqrt(tot);
    xn[row] = fmaxf(n, CEPS);
  }
}

// ---- concept magnitude (transposed) + norms ----
__device__ __forceinline__ void dev_cmag(double* red, const float* __restrict__ cre,
                                         const float* __restrict__ cim, float* __restrict__ cmagT,
                                         float* __restrict__ yn, int c) {
  const float* r = cre + (size_t)c * 512;
  const float* q = cim + (size_t)c * 512;
  double ss = 0.0;
  for (int d = threadIdx.x; d < 512; d += 256) {
    float a = r[d], b = q[d];
    float s = __fadd_rn(__fmul_rn(a, a), __fmul_rn(b, b));
    float m = __fsqrt_rn(s);
    cmagT[(size_t)d * 1000 + c] = m;
    ss += (double)m * (double)m;
  }
  for (int off = 32; off; off >>= 1) ss += __shfl_xor(ss, off);
  int lane = threadIdx.x & 63, wave = threadIdx.x >> 6;
  if (lane == 0) red[wave] = ss;
  __syncthreads();
  if (threadIdx.x == 0) {
    double tot = red[0] + red[1] + red[2] + red[3];
    float n = (float)sqrt(tot);
    yn[c] = fmaxf(n, CEPS);
  }
}

// ---- transpose: W[K,N] f32 -> Wt[n][k] (OUTT 0=bf16, 1=fp8; zero-pad n>=N) ----
template <int OUTT>
__device__ __forceinline__ void dev_tr(float (*t32)[65], const float* __restrict__ W,
                                       void* __restrict__ Wt, int K, int N, int bx, int by) {
  int n0 = bx * 64, k0 = by * 64;
  int tid = threadIdx.x;
  {
    int nc = tid & 15, kr4 = tid >> 4;
#pragma unroll
    for (int p = 0; p < 4; ++p) {
      int kr = p * 16 + kr4;
      int n = n0 + nc * 4;
      float4 v = make_float4(0.f, 0.f, 0.f, 0.f);
      if (n < N) v = *(const float4*)(W + (size_t)(k0 + kr) * N + n);
      t32[kr][nc * 4 + 0] = v.x; t32[kr][nc * 4 + 1] = v.y;
      t32[kr][nc * 4 + 2] = v.z; t32[kr][nc * 4 + 3] = v.w;
    }
  }
  __syncthreads();
  {
    int kc = tid & 15, nr4 = tid >> 4;
#pragma unroll
    for (int p = 0; p < 4; ++p) {
      int nr = p * 16 + nr4;
      if (OUTT == 0) {
        ushort4 o;
        __hip_bfloat16 h0 = __float2bfloat16(t32[kc * 4 + 0][nr]);
        __hip_bfloat16 h1 = __float2bfloat16(t32[kc * 4 + 1][nr]);
        __hip_bfloat16 h2 = __float2bfloat16(t32[kc * 4 + 2][nr]);
        __hip_bfloat16 h3 = __float2bfloat16(t32[kc * 4 + 3][nr]);
        o.x = *(unsigned short*)&h0; o.y = *(unsigned short*)&h1;
        o.z = *(unsigned short*)&h2; o.w = *(unsigned short*)&h3;
        *(ushort4*)((unsigned short*)Wt + (size_t)(n0 + nr) * K + k0 + kc * 4) = o;
      } else {
        unsigned int o = (unsigned int)f32_to_e4m3(t32[kc * 4 + 0][nr]) |
                         ((unsigned int)f32_to_e4m3(t32[kc * 4 + 1][nr]) << 8) |
                         ((unsigned int)f32_to_e4m3(t32[kc * 4 + 2][nr]) << 16) |
                         ((unsigned int)f32_to_e4m3(t32[kc * 4 + 3][nr]) << 24);
        *(unsigned int*)((unsigned char*)Wt + (size_t)(n0 + nr) * K + k0 + kc * 4) = o;
      }
    }
  }
}

// ---- 128x128 bf16 MFMA GEMM with gelu epilogue (MLP layers) ----
template <int OUTT>
__device__ __forceinline__ void dev_mlp(short* Al, short* Bl, const __hip_bfloat16* __restrict__ A,
                                        const __hip_bfloat16* __restrict__ Bt, void* __restrict__ C,
                                        int M, int N, int K, int ldc, const float* __restrict__ bias,
                                        int bx, int by) {
  const int tid = threadIdx.x, lane = tid & 63, wave = tid >> 6;
  const int m0 = by * 128, n0 = bx * 128;
  const int wr = wave >> 1, wc = wave & 1;
  f32x4 acc[4][4];
  f32x4 zero4 = {0.f, 0.f, 0.f, 0.f};
#pragma unroll
  for (int i = 0; i < 4; ++i)
#pragma unroll
    for (int j = 0; j < 4; ++j) acc[i][j] = zero4;

  const short* Ag = (const short*)A;
  const short* Bg = (const short*)Bt;
  for (int k0 = 0; k0 < K; k0 += 32) {
#pragma unroll
    for (int s = 0; s < 2; ++s) {
      int seg = wave + s * 4;
      int elem = seg * 512 + lane * 8;
      int row = elem >> 5, kk = elem & 31;
      gload_lds16(Ag + (size_t)(m0 + row) * K + k0 + kk, Al + elem);
      gload_lds16(Bg + (size_t)(n0 + row) * K + k0 + kk, Bl + elem);
    }
    __syncthreads();
    bf16x8 af[4], bfr[4];
    const int fr = lane & 15, fk = (lane >> 4) << 3;
#pragma unroll
    for (int i = 0; i < 4; ++i)
      af[i] = *(const bf16x8*)(Al + (wr * 64 + i * 16 + fr) * 32 + fk);
#pragma unroll
    for (int j = 0; j < 4; ++j)
      bfr[j] = *(const bf16x8*)(Bl + (wc * 64 + j * 16 + fr) * 32 + fk);
#pragma unroll
    for (int i = 0; i < 4; ++i)
#pragma unroll
      for (int j = 0; j < 4; ++j)
        acc[i][j] = __builtin_amdgcn_mfma_f32_16x16x32_bf16(af[i], bfr[j], acc[i][j], 0, 0, 0);
    __syncthreads();
  }
  const int fr = lane & 15, fq = lane >> 4;
#pragma unroll
  for (int j = 0; j < 4; ++j) {
    int col = n0 + wc * 64 + j * 16 + fr;
    if (col >= N) continue;
    float bv = bias[col];
#pragma unroll
    for (int i = 0; i < 4; ++i) {
      int rbase = m0 + wr * 64 + i * 16 + fq * 4;
#pragma unroll
      for (int r = 0; r < 4; ++r) {
        float v = gelu_f(acc[i][j][r] + bv);
        if (OUTT == 0)
          ((__hip_bfloat16*)C)[(size_t)(rbase + r) * ldc + col] = __float2bfloat16(v);
        else
          ((unsigned char*)C)[(size_t)(rbase + r) * ldc + col] = f32_to_e4m3(v);
      }
    }
  }
}

// ---- dots GEMM, f64 acc; LDS padded [16][65] (conflict-free); FMA order = rounds 7-11 ----
__device__ __forceinline__ void dev_dots(double (*As)[65], double (*Bs)[65],
                                         const float* __restrict__ A, const float* __restrict__ Bm,
                                         float* __restrict__ Cm, int M, int N, int K, int ldc,
                                         const float* __restrict__ xn, const float* __restrict__ yn,
                                         int nb, int mb) {
  const int tid = threadIdx.x;
  const int m0 = mb * 64, n0 = nb * 64;
  const int tx = tid & 15, ty4 = tid >> 4;
  const int ar = tid >> 2, ak = (tid & 3) << 2;
  const int bk = tid >> 4, bn = (tid & 15) << 2;
  double acc[4][4] = {};
  for (int k0 = 0; k0 < K; k0 += 16) {
    float4 a4 = *(const float4*)(A + (size_t)(m0 + ar) * K + k0 + ak);
    As[ak + 0][ar] = (double)a4.x; As[ak + 1][ar] = (double)a4.y;
    As[ak + 2][ar] = (double)a4.z; As[ak + 3][ar] = (double)a4.w;
    float4 b4 = make_float4(0.f, 0.f, 0.f, 0.f);
    if (n0 + bn < N) b4 = *(const float4*)(Bm + (size_t)(k0 + bk) * N + n0 + bn);
    Bs[bk][bn + 0] = (double)b4.x; Bs[bk][bn + 1] = (double)b4.y;
    Bs[bk][bn + 2] = (double)b4.z; Bs[bk][bn + 3] = (double)b4.w;
    __syncthreads();
#pragma unroll
    for (int kk = 0; kk < 16; ++kk) {
      double av[4], bv[4];
#pragma unroll
      for (int i = 0; i < 4; ++i) av[i] = As[kk][ty4 + i * 16];
#pragma unroll
      for (int j = 0; j < 4; ++j) bv[j] = Bs[kk][tx + j * 16];
#pragma unroll
      for (int i = 0; i < 4; ++i)
#pragma unroll
        for (int j = 0; j < 4; ++j)
          acc[i][j] = fma(av[i], bv[j], acc[i][j]);
    }
    __syncthreads();
  }
#pragma unroll
  for (int i = 0; i < 4; ++i) {
    int row = m0 + ty4 + i * 16;
#pragma unroll
    for (int j = 0; j < 4; ++j) {
      int col = n0 + tx + j * 16;
      if (col >= N) continue;
      double d = acc[i][j] / ((double)xn[row] * (double)yn[col]);
      Cm[(size_t)row * ldc + col] = (float)d;
    }
  }
}

// ---- top-5 per row (one wave per row; 4 rows per block) ----
__device__ __forceinline__ void dev_topk(const float* __restrict__ sims,
                                         float* __restrict__ top_sims, float* __restrict__ top_idx,
                                         int rowblock) {
  int lane = threadIdx.x & 63, wave = threadIdx.x >> 6;
  int row = rowblock * 4 + wave;
  const float* s = sims + (size_t)row * 1000;
  float v[16];
  int idx[16];
#pragma unroll
  for (int t = 0; t < 16; ++t) {
    int c = lane + t * 64;
    if (c < 1000) { v[t] = s[c]; idx[t] = c; }
    else { v[t] = -1e30f; idx[t] = 1 << 20; }
  }
  for (int j = 0; j < 5; ++j) {
    float bv = -1e30f; int bi = 1 << 20;
#pragma unroll
    for (int t = 0; t < 16; ++t) {
      if (v[t] > bv || (v[t] == bv && idx[t] < bi)) { bv = v[t]; bi = idx[t]; }
    }
    float rv = bv; int ri = bi;
#pragma unroll
    for (int off = 32; off; off >>= 1) {
      float ov = __shfl_xor(rv, off);
      int oi = __shfl_xor(ri, off);
      if (ov > rv || (ov == rv && oi < ri)) { rv = ov; ri = oi; }
    }
    if (lane == 0) {
      top_sims[(size_t)row * 5 + j] = rv;
      top_idx[(size_t)row * 5 + j] = (float)ri;
    }
#pragma unroll
    for (int t = 0; t < 16; ++t)
      if (idx[t] == ri) v[t] = -1e30f;
  }
}

// ================= fused launches =================

// launch 1: trW1(128) | trW2(64) | trW3(96) | cmag(1000) | mag(2048)  = 3336 blocks
__global__ __launch_bounds__(256) void k_pre(const float* W1, __hip_bfloat16* w1t,
                                             const float* W2, __hip_bfloat16* w2t,
                                             const float* W3, __hip_bfloat16* w3t,
                                             const float* cre, const float* cim, float* cmagT, float* yn,
                                             const float* sre, const float* simg, float* mag,
                                             __hip_bfloat16* xcat, float* xn) {
  __shared__ float t32[64][65];
  __shared__ double red[4];
  int bid = blockIdx.x;
  if (bid < 128) {
    dev_tr<0>(t32, W1, (void*)w1t, 1024, 512, bid & 7, bid >> 3);
  } else if (bid < 192) {
    int t = bid - 128;
    dev_tr<0>(t32, W2, (void*)w2t, 512, 512, t & 7, t >> 3);
  } else if (bid < 288) {
    int t = bid - 192;
    dev_tr<0>(t32, W3, (void*)w3t, 512, 768, t % 12, t / 12);
  } else if (bid < 1288) {
    dev_cmag(red, cre, cim, cmagT, yn, bid - 288);
  } else {
    dev_mag(red, sre, simg, mag, xcat, xn, bid - 1288);
  }
}

// launch 2: MLP-L1 (64) | dots (512) | trW4 fp8 (9408)
union L1W4Smem {
  struct { short Al[128 * 32]; short Bl[128 * 32]; } m;
  float t32[64][65];
  struct { double As[16][65]; double Bs[16][65]; } d;
};
__global__ __launch_bounds__(256) void k_l1w4(const __hip_bfloat16* xcat, const __hip_bfloat16* w1t,
                                              __hip_bfloat16* h1b, const float* b1,
                                              const float* W4, unsigned char* w4f8,
                                              const float* mag, const float* cmagT, float* simsb,
                                              const float* xn, const float* yn) {
  __shared__ L1W4Smem sm;
  int bid = blockIdx.x;
  if (bid < 64) {
    dev_mlp<0>(sm.m.Al, sm.m.Bl, xcat, w1t, (void*)h1b, 2048, 512, 1024, 512, b1, bid & 3, bid >> 2);
  } else if (bid < 576) {
    int id = bid - 64;  // 0..511
    dev_dots(sm.d.As, sm.d.Bs, mag, cmagT, simsb, 2048, 1000, 512, 1000, xn, yn,
             id & 15, id >> 4);
  } else {
    int t = bid - 576;
    dev_tr<1>(sm.t32, W4, (void*)w4f8, 768, 50000, t % 784, t / 784);
  }
}

// launch 3: MLP-L2 (64, bf16 out) | topk (512)
__global__ __launch_bounds__(256) void k_l2topk(const __hip_bfloat16* h1b, const __hip_bfloat16* w2t,
                                                __hip_bfloat16* h2b, const float* b2,
                                                const float* simsb, float* top_sims, float* top_idx) {
  __shared__ short Al[128 * 32];
  __shared__ short Bl[128 * 32];
  int bid = blockIdx.x;
  if (bid < 64) {
    dev_mlp<0>(Al, Bl, h1b, w2t, (void*)h2b, 2048, 512, 512, 512, b2, bid & 3, bid >> 2);
  } else {
    dev_topk(simsb, top_sims, top_idx, bid - 64);
  }
}

// launch 4: MLP-L3 (fp8 out)
__global__ __launch_bounds__(256) void k_l3(const __hip_bfloat16* h2b, const __hip_bfloat16* w3t,
                                            unsigned char* h3f8, const float* b3) {
  __shared__ short Al[128 * 32];
  __shared__ short Bl[128 * 32];
  dev_mlp<1>(Al, Bl, h2b, w3t, (void*)h3f8, 2048, 768, 512, 768, b3, blockIdx.x % 6, blockIdx.x / 6);
}

// launch 5: final-layer fp8 GEMM — 256Mx128N tile, BK=64, dbuf 48KB LDS, **512 thr / 8 waves**.
// Change vs r9: 8 waves per block -> 2 blocks/CU x 8 = 16 waves/CU = 4 waves/SIMD (was 2).
// Per-wave output 64x64 (acc 64 VGPR); __launch_bounds__(512,4) caps VGPR at 128.
// Counted vmcnt(3) (3 gloads/thread/K-tile, next tile in flight). Swizzle + swapped-MFMA kept.
__global__ __launch_bounds__(512, 4) void k_main(const unsigned char* __restrict__ A8,
                                                 const unsigned char* __restrict__ B8,
                                                 float* __restrict__ C, const float* __restrict__ bias) {
  const int KNT = 12;
  const int Kd = 768, Nd = 50000, ldc = 50000;
  __shared__ unsigned char As[2][16384];  // 256 rows x 64 B
  __shared__ unsigned char Bs[2][8192];   // 128 rows x 64 B
  const int tid = threadIdx.x, lane = tid & 63, wave = tid >> 6;
  const int wm = wave & 3, wn = wave >> 2;  // 4M x 2N waves, per-wave 64x64

  const int xcd = blockIdx.x & 7, j = blockIdx.x >> 3;
  const int mt = j & 7;
  const int ntile = xcd + 8 * (j >> 3);
  const int m0 = mt * 256, n0 = ntile * 128;

  f32x4 acc[4][4];
  f32x4 z4 = {0.f, 0.f, 0.f, 0.f};
#pragma unroll
  for (int q = 0; q < 4; ++q)
#pragma unroll
    for (int p = 0; p < 4; ++p) acc[q][p] = z4;

  // stage K-tile kt: A 2 gloads/thread, B 1 gload/thread (3 VMEM/thread/K-tile)
  auto stageA = [&](int kt, int buf) {
    if (kt >= KNT) return;
    const int k0 = kt * 64;
#pragma unroll
    for (int r = 0; r < 2; ++r) {
      int idx = r * 512 + tid;           // 0..1023 16B-chunks
      int row = idx >> 2, c = idx & 3;
      int src = ((c * 2) ^ (row & 6)) * 8;  // 16B-contiguous (row&6 even)
      gload_lds16(A8 + (size_t)(m0 + row) * Kd + k0 + src, &As[buf][row * 64 + c * 16]);
    }
  };
  auto stageB = [&](int kt, int buf) {
    if (kt >= KNT) return;
    const int k0 = kt * 64;
    {
      int idx = tid;                     // 0..511
      int row = idx >> 2, c = idx & 3;
      int src = ((c * 2) ^ (row & 6)) * 8;
      gload_lds16(B8 + (size_t)(n0 + row) * Kd + k0 + src, &Bs[buf][row * 64 + c * 16]);
    }
  };

  stageA(0, 0); stageB(0, 0);
  stageA(1, 1); stageB(1, 1);

  for (int g = 0; g < KNT; ++g) {
    const int buf = g & 1;
    if (g < KNT - 1) asm volatile("s_waitcnt vmcnt(3)" ::: "memory");  // tile g landed
    else             asm volatile("s_waitcnt vmcnt(0)" ::: "memory");
    __builtin_amdgcn_sched_barrier(0);
    __builtin_amdgcn_s_barrier();
    __builtin_amdgcn_sched_barrier(0);

    long bfr[4][2];
#pragma unroll
    for (int p = 0; p < 4; ++p) {
      int row = wn * 64 + p * 16 + (lane & 15);
#pragma unroll
      for (int kh = 0; kh < 2; ++kh) {
        int slot = (kh * 4 + (lane >> 4)) ^ (row & 6);
        bfr[p][kh] = *(const long*)(&Bs[buf][row * 64 + slot * 8]);
      }
    }
    __builtin_amdgcn_s_setprio(1);
#pragma unroll
    for (int q = 0; q < 4; ++q) {
      int rowA = wm * 64 + q * 16 + (lane & 15);
      long af[2];
#pragma unroll
      for (int kh = 0; kh < 2; ++kh) {
        int slot = (kh * 4 + (lane >> 4)) ^ (rowA & 6);
        af[kh] = *(const long*)(&As[buf][rowA * 64 + slot * 8]);
      }
#pragma unroll
      for (int kh = 0; kh < 2; ++kh)
#pragma unroll
        for (int p = 0; p < 4; ++p)
          acc[q][p] = __builtin_amdgcn_mfma_f32_16x16x32_fp8_fp8(bfr[p][kh], af[kh], acc[q][p], 0, 0, 0);
    }
    __builtin_amdgcn_s_setprio(0);

    __builtin_amdgcn_sched_barrier(0);
    __builtin_amdgcn_s_barrier();
    __builtin_amdgcn_sched_barrier(0);
    stageA(g + 2, buf);
    stageB(g + 2, buf);
  }

  // epilogue: bias + float4 stores (swapped layout: per lane 1 row, 4 consecutive cols)
  const int colq = (lane >> 4) * 4;
  float4 bias4[4];
#pragma unroll
  for (int p = 0; p < 4; ++p) {
    int colbase = n0 + wn * 64 + p * 16 + colq;
    bias4[p] = (colbase < Nd) ? *(const float4*)(bias + colbase) : make_float4(0.f, 0.f, 0.f, 0.f);
  }
#pragma unroll
  for (int q = 0; q < 4; ++q) {
    int row = m0 + wm * 64 + q * 16 + (lane & 15);
#pragma unroll
    for (int p = 0; p < 4; ++p) {
      int colbase = n0 + wn * 64 + p * 16 + colq;
      if (colbase < Nd) {
        f32x4 v = acc[q][p];
        float4 o = make_float4(v[0] + bias4[p].x, v[1] + bias4[p].y,
                               v[2] + bias4[p].z, v[3] + bias4[p].w);
        *(float4*)(&C[(size_t)row * ldc + colbase]) = o;
      }
    }
  }
}

extern "C" void kernel_launch(void* const* d_in, const int* in_sizes, int n_in,
                              void* d_out, int out_size, void* d_ws, size_t ws_size,
                              hipStream_t stream) {
  const float* sre = (const float*)d_in[0];
  const float* simg = (const float*)d_in[1];
  const float* cre = (const float*)d_in[2];
  const float* cim = (const float*)d_in[3];
  const float* W1 = (const float*)d_in[4];
  const float* b1 = (const float*)d_in[5];
  const float* W2 = (const float*)d_in[6];
  const float* b2 = (const float*)d_in[7];
  const float* W3 = (const float*)d_in[8];
  const float* b3 = (const float*)d_in[9];
  const float* W4 = (const float*)d_in[10];
  const float* b4 = (const float*)d_in[11];

  const int M = 2048, D = 512, Cc = 1000, V = 50000, K1 = 1024, H3 = 768;
  const int Npad2 = 392 * 128;  // 50176

  char* ws = (char*)d_ws;
  size_t off = 0;
  auto alloc = [&](size_t bytes) {
    char* p = ws + off;
    off = (off + bytes + 255) & ~(size_t)255;
    return p;
  };
  __hip_bfloat16* xcatb = (__hip_bfloat16*)alloc((size_t)M * K1 * 2);
  float* mag = (float*)alloc((size_t)M * D * 4);
  float* cmagT = (float*)alloc((size_t)D * Cc * 4);
  float* xn = (float*)alloc((size_t)M * 4);
  float* yn = (float*)alloc((size_t)Cc * 4);
  float* simsb = (float*)alloc((size_t)M * Cc * 4);
  __hip_bfloat16* h1b = (__hip_bfloat16*)alloc((size_t)M * 512 * 2);
  __hip_bfloat16* h2b = (__hip_bfloat16*)alloc((size_t)M * 512 * 2);
  unsigned char* h3f8 = (unsigned char*)alloc((size_t)M * H3);
  __hip_bfloat16* w1t = (__hip_bfloat16*)alloc((size_t)512 * K1 * 2);
  __hip_bfloat16* w2t = (__hip_bfloat16*)alloc((size_t)512 * 512 * 2);
  __hip_bfloat16* w3t = (__hip_bfloat16*)alloc((size_t)H3 * 512 * 2);
  unsigned char* w4f8 = (unsigned char*)alloc((size_t)Npad2 * H3);

  float* top_sims = (float*)d_out;
  float* top_idx = (float*)d_out + (size_t)M * 5;
  float* logits = (float*)d_out + (size_t)M * 5 * 2;

  // 1: weight transposes W1-3 + cmag + mag (all independent)
  k_pre<<<dim3(3336), dim3(256), 0, stream>>>(W1, w1t, W2, w2t, W3, w3t,
                                              cre, cim, cmagT, yn, sre, simg, mag, xcatb, xn);
  // 2: MLP-L1 + dots + W4 transpose
  k_l1w4<<<dim3(64 + 512 + 9408), dim3(256), 0, stream>>>(xcatb, w1t, h1b, b1, W4, w4f8,
                                                          mag, cmagT, simsb, xn, yn);
  // 3: MLP-L2 + top-k
  k_l2topk<<<dim3(64 + 512), dim3(256), 0, stream>>>(h1b, w2t, h2b, b2, simsb, top_sims, top_idx);
  // 4: MLP-L3
  k_l3<<<dim3(96), dim3(256), 0, stream>>>(h2b, w3t, h3f8, b3);
  // 5: big fp8 GEMM (512 thr, 4 waves/SIMD)
  k_main<<<dim3(3136), dim3(512), 0, stream>>>(h3f8, w4f8, logits, b4);
}